// Round 16
// baseline (482.645 us; speedup 1.0000x reference)
//
#include <hip/hip_runtime.h>
#include <cstdint>
#include <cstddef>

#define NN 50000
#define NPAD 50048            // 391 * 128
#define EE 800000
#define ET (EE + NN)
#define GG 64
#define HH 4
#define RSQ 0.9999950000374997f   // 1/sqrt(1+1e-5)

typedef short bf16x8 __attribute__((ext_vector_type(8)));
typedef unsigned short u16x8 __attribute__((ext_vector_type(8)));
typedef float f32x4 __attribute__((ext_vector_type(4)));
typedef float f32x2 __attribute__((ext_vector_type(2)));

__device__ __forceinline__ float bf2f(unsigned short u) {
    union { unsigned int i; float f; } v; v.i = ((unsigned int)u) << 16; return v.f;
}
__device__ __forceinline__ unsigned short f2bf(float f) {
    union { float f; unsigned int i; } v; v.f = f;
    unsigned int u = v.i;
    u += 0x7fffu + ((u >> 16) & 1u);
    return (unsigned short)(u >> 16);
}
// bf16-pair decode: lo/hi halves of a dword ARE truncated f32s.
__device__ __forceinline__ float bflo(unsigned int u) { return __uint_as_float(u << 16); }
__device__ __forceinline__ float bfhi(unsigned int u) { return __uint_as_float(u & 0xffff0000u); }

#if __has_builtin(__builtin_amdgcn_readlane)
#define READLANE(v, l) __builtin_amdgcn_readlane((v), (l))
#else
#define READLANE(v, l) __shfl((v), (l))
#endif

static inline void* carve(char*& p, size_t bytes) {
    void* r = (void*)p;
    p += (bytes + 255) & ~(size_t)255;
    return r;
}

// ----------------------------------------------------- init (replaces memsets)

__global__ void zero_kernel(int* __restrict__ deg, float* __restrict__ pooled,
                            int* __restrict__ first, int* __restrict__ last) {
    int i = blockIdx.x * blockDim.x + threadIdx.x;
    if (i < NN) deg[i] = 0;
    int j = i - NN;
    if (j >= 0 && j < GG * 256) pooled[j] = 0.f;
    int k = j - GG * 256;
    if (k >= 0 && k < GG) { first[k] = 0; last[k] = -1; }
}

// ------------------------------------------------------------- CSR building

__global__ void deg_kernel(const int* __restrict__ dst0, int* __restrict__ deg,
                           int* __restrict__ epos) {
    int e = blockIdx.x * blockDim.x + threadIdx.x;
    if (e >= EE) return;
    epos[e] = atomicAdd(&deg[dst0[e]], 1);
}

#define SCAN_B 512
__global__ void scan1_kernel(const int* __restrict__ deg, int* __restrict__ out,
                             int* __restrict__ bsum, int n) {
    __shared__ int tmp[SCAN_B];
    int i = blockIdx.x * SCAN_B + threadIdx.x;
    int v = (i < n) ? (deg[i] + 1) : 0;   // +1 self loop
    tmp[threadIdx.x] = v;
    __syncthreads();
    for (int off = 1; off < SCAN_B; off <<= 1) {
        int t = (threadIdx.x >= off) ? tmp[threadIdx.x - off] : 0;
        __syncthreads();
        tmp[threadIdx.x] += t;
        __syncthreads();
    }
    if (i < n) out[i] = tmp[threadIdx.x] - v;       // exclusive
    if (threadIdx.x == SCAN_B - 1) bsum[blockIdx.x] = tmp[threadIdx.x];
}

__global__ void scan2_kernel(int* __restrict__ bsum, int nb) {
    __shared__ int tmp[128];
    int v = (threadIdx.x < nb) ? bsum[threadIdx.x] : 0;
    tmp[threadIdx.x] = v;
    __syncthreads();
    for (int off = 1; off < 128; off <<= 1) {
        int t = (threadIdx.x >= off) ? tmp[threadIdx.x - off] : 0;
        __syncthreads();
        tmp[threadIdx.x] += t;
        __syncthreads();
    }
    if (threadIdx.x < nb) bsum[threadIdx.x] = tmp[threadIdx.x] - v;  // exclusive
}

__global__ void scan3_kernel(int* __restrict__ out, const int* __restrict__ bsum, int n) {
    int i = blockIdx.x * SCAN_B + threadIdx.x;
    if (i < n) out[i] += bsum[blockIdx.x];
    if (i == 0 && blockIdx.x == 0) out[n] = ET;
}

// merged fill: edges then self-loops; also reorders ef into CSR order (efc).
__global__ void fill_kernel(const int* __restrict__ src0, const int* __restrict__ dst0,
                            const int* __restrict__ row_ptr, const int* __restrict__ epos,
                            const int* __restrict__ deg, const float* __restrict__ ef,
                            int* __restrict__ ssrc, float* __restrict__ efc) {
    int e = blockIdx.x * blockDim.x + threadIdx.x;
    if (e < EE) {
        int idx = row_ptr[dst0[e]] + epos[e];
        ssrc[idx] = src0[e];
        const float* s6 = &ef[(size_t)e * 6];
        float* d6 = &efc[(size_t)idx * 6];
        *(float2*)&d6[0] = *(const float2*)&s6[0];
        *(float2*)&d6[2] = *(const float2*)&s6[2];
        *(float2*)&d6[4] = *(const float2*)&s6[4];
    } else if (e < ET) {
        int n = e - EE;
        int idx = row_ptr[n] + deg[n];   // self loop: last slot of the segment
        ssrc[idx] = n;
        float* d6 = &efc[(size_t)idx * 6];
        float2 z = make_float2(0.f, 0.f);
        *(float2*)&d6[0] = z; *(float2*)&d6[2] = z; *(float2*)&d6[4] = z;
    }
}

// -------------------------------------------- prep: convx + convw x3 + wea x3

#define PREP_X  (NPAD * 64)
#define PREP_W1 (PREP_X + 16384)
#define PREP_W2 (PREP_W1 + 131072)
#define PREP_W3 (PREP_W2 + 131072)
#define PREP_T  (PREP_W3 + 128)

__global__ void prep_kernel(const float* __restrict__ x,
                            const float* __restrict__ W1, const float* __restrict__ W2,
                            const float* __restrict__ W3,
                            const float* __restrict__ We1, const float* __restrict__ ae1,
                            const float* __restrict__ We2, const float* __restrict__ ae2,
                            const float* __restrict__ We3, const float* __restrict__ ae3,
                            unsigned short* __restrict__ B0,
                            unsigned short* __restrict__ Wt1, unsigned short* __restrict__ Wt2,
                            unsigned short* __restrict__ Wt3, float* __restrict__ Wea) {
    int i = blockIdx.x * blockDim.x + threadIdx.x;
    if (i < PREP_X) {
        int row = i >> 6, col = i & 63;
        float v = 0.f;
        if (row < NN && col < 32) v = x[(size_t)row * 32 + col];
        B0[i] = f2bf(v);
    } else if (i < PREP_W1) {
        int j = i - PREP_X;
        int c = j >> 6, k = j & 63;
        Wt1[j] = (k < 32) ? f2bf(W1[(size_t)k * 256 + c]) : (unsigned short)0;
    } else if (i < PREP_W2) {
        int j = i - PREP_W1;
        int c = j >> 8, k = j & 255;
        Wt2[j] = f2bf(W2[(size_t)k * 512 + c]);
    } else if (i < PREP_W3) {
        int j = i - PREP_W2;
        int c = j >> 9, k = j & 511;
        Wt3[j] = f2bf(W3[(size_t)k * 256 + c]);
    } else if (i < PREP_T) {
        int t = i - PREP_W3;
        if (t < 72) {
            int l = t / 24, w = t % 24, k = w / 4, h = w % 4;
            const float* We = (l == 0) ? We1 : (l == 1) ? We2 : We3;
            const float* ae = (l == 0) ? ae1 : (l == 1) ? ae2 : ae3;
            int C = (l == 1) ? 128 : 64;
            int HC = 4 * C;
            float s = 0.f;
            for (int c = 0; c < C; c++) s += We[(size_t)k * HC + h * C + c] * ae[(size_t)h * C + c];
            Wea[l * 24 + k * 4 + h] = s;
        }
    }
}

// ------------------------------------------------------------ bf16 MFMA GEMM
// m97-style staging + FUSED epilogue: bf16 mirror Xb + attention dots.

#if __has_builtin(__builtin_amdgcn_global_load_lds)
#define GLL_OK 1
#else
#define GLL_OK 0
#endif

#define TILE_LD 136

template <int C_>
__global__ __launch_bounds__(256) void gemm_fused_kernel(const unsigned short* __restrict__ A,
                                                         const unsigned short* __restrict__ Bt,
                                                         unsigned short* __restrict__ Xb,
                                                         const float* __restrict__ a_s,
                                                         const float* __restrict__ a_d,
                                                         float* __restrict__ als,
                                                         float* __restrict__ ald,
                                                         int K) {
    constexpr int HC = HH * C_;
    __shared__ unsigned short smem[128 * TILE_LD + 64];
    unsigned short* As = smem;
    unsigned short* Bs = smem + 8192;
    const int tid = threadIdx.x;
    const int bm = blockIdx.x * 128;
    const int bn = blockIdx.y * 128;
    const int lane = tid & 63;
    const int wv = tid >> 6;
    const int wrow = (wv >> 1) * 64;
    const int wcol = (wv & 1) * 64;
    const int l15 = lane & 15;
    const int q = lane >> 4;

    f32x4 acc[4][4];
#pragma unroll
    for (int m = 0; m < 4; m++)
#pragma unroll
        for (int n = 0; n < 4; n++) acc[m][n] = (f32x4)0.f;

    for (int k0 = 0; k0 < K; k0 += 64) {
#pragma unroll
        for (int i = 0; i < 4; i++) {
            int c = (wv * 4 + i) * 64 + lane;
            int row = c >> 3, slot = c & 7;
            int slotG = slot ^ (row & 7);
            const unsigned short* ga = &A[(size_t)(bm + row) * K + k0 + slotG * 8];
            const unsigned short* gb = &Bt[(size_t)(bn + row) * K + k0 + slotG * 8];
#if GLL_OK
            __builtin_amdgcn_global_load_lds(
                (const __attribute__((address_space(1))) unsigned int*)ga,
                (__attribute__((address_space(3))) unsigned int*)&As[(size_t)(wv * 4 + i) * 512],
                16, 0, 0);
            __builtin_amdgcn_global_load_lds(
                (const __attribute__((address_space(1))) unsigned int*)gb,
                (__attribute__((address_space(3))) unsigned int*)&Bs[(size_t)(wv * 4 + i) * 512],
                16, 0, 0);
#else
            *(u16x8*)&As[(size_t)c * 8] = *(const u16x8*)ga;
            *(u16x8*)&Bs[(size_t)c * 8] = *(const u16x8*)gb;
#endif
        }
        __syncthreads();
#pragma unroll
        for (int kk = 0; kk < 2; kk++) {
            bf16x8 af[4], bfr[4];
#pragma unroll
            for (int m = 0; m < 4; m++) {
                int ra = wrow + m * 16 + l15;
                af[m] = *(const bf16x8*)&As[ra * 64 + ((kk * 4 + q) ^ (ra & 7)) * 8];
            }
#pragma unroll
            for (int n = 0; n < 4; n++) {
                int rb = wcol + n * 16 + l15;
                bfr[n] = *(const bf16x8*)&Bs[rb * 64 + ((kk * 4 + q) ^ (rb & 7)) * 8];
            }
#pragma unroll
            for (int m = 0; m < 4; m++)
#pragma unroll
                for (int n = 0; n < 4; n++)
                    acc[m][n] = __builtin_amdgcn_mfma_f32_16x16x32_bf16(af[m], bfr[n], acc[m][n], 0, 0, 0);
        }
        __syncthreads();
    }

    unsigned short* tile = smem;  // reuse; 128 x TILE_LD
#pragma unroll
    for (int m = 0; m < 4; m++) {
#pragma unroll
        for (int n = 0; n < 4; n++) {
#pragma unroll
            for (int j = 0; j < 4; j++) {
                int r = wrow + m * 16 + (lane >> 4) * 4 + j;
                int c = wcol + n * 16 + l15;
                tile[r * TILE_LD + c] = f2bf(acc[m][n][j]);    // m89-verified mapping
            }
        }
    }
    __syncthreads();

    const int tcol = tid & 15;
    const int trow = tid >> 4;
    float as8[8], ad8[8];
#pragma unroll
    for (int k = 0; k < 8; k++) {
        as8[k] = a_s[bn + tcol * 8 + k];
        ad8[k] = a_d[bn + tcol * 8 + k];
    }
#pragma unroll
    for (int i = 0; i < 8; i++) {
        int r = i * 16 + trow;
        int grow = bm + r;
        u16x8 v = *(const u16x8*)&tile[r * TILE_LD + tcol * 8];
        *(u16x8*)&Xb[(size_t)grow * HC + bn + tcol * 8] = v;   // bf16 mirror, plain copy
        float f[8];
#pragma unroll
        for (int k = 0; k < 8; k++) f[k] = bf2f((unsigned short)v[k]);
        float ps = 0.f, pd = 0.f;
#pragma unroll
        for (int k = 0; k < 8; k++) { ps += f[k] * as8[k]; pd += f[k] * ad8[k]; }
        if constexpr (C_ == 64) {
            ps += __shfl_xor(ps, 1); pd += __shfl_xor(pd, 1);
            ps += __shfl_xor(ps, 2); pd += __shfl_xor(pd, 2);
            ps += __shfl_xor(ps, 4); pd += __shfl_xor(pd, 4);
            if ((tid & 7) == 0 && grow < NN) {
                int head = (bn >> 6) + (tcol >> 3);
                als[(size_t)grow * HH + head] = ps;
                ald[(size_t)grow * HH + head] = pd;
            }
        } else {
            ps += __shfl_xor(ps, 1); pd += __shfl_xor(pd, 1);
            ps += __shfl_xor(ps, 2); pd += __shfl_xor(pd, 2);
            ps += __shfl_xor(ps, 4); pd += __shfl_xor(pd, 4);
            ps += __shfl_xor(ps, 8); pd += __shfl_xor(pd, 8);
            if ((tid & 15) == 0 && grow < NN) {
                int head = bn >> 7;
                als[(size_t)grow * HH + head] = ps;
                ald[(size_t)grow * HH + head] = pd;
            }
        }
    }
}

// --- FUSED per-node: emean + logits + leaky + softmax + bf16 aggregation
//     + bias + BN + ELU.  Gather: s via READLANE (scalar row base),
//     ww via one shfl broadcast; bf16 decode = 2 bit-ops per dword.

template <int C_>
__global__ __launch_bounds__(256) void aggregate_fused_kernel(
        const unsigned short* __restrict__ xsb,
        const int* __restrict__ rowptr, const int* __restrict__ ssrc,
        const float* __restrict__ efc, const float* __restrict__ Wea,
        const float* __restrict__ als, const float* __restrict__ ald,
        float* __restrict__ al,
        const float* __restrict__ bias, const float* __restrict__ gam,
        const float* __restrict__ bet, unsigned short* __restrict__ hout) {
    constexpr int HC = HH * C_;
    constexpr int CPL = HC / 64;   // channels/lane: 4 (HC=256) or 8 (HC=512)
    int wid = (blockIdx.x * blockDim.x + threadIdx.x) >> 6;
    int lane = threadIdx.x & 63;
    if (wid >= NN) return;
    int b = rowptr[wid], e = rowptr[wid + 1];
    int cnt = e - b;
    const int hpre = lane >> 4;
    const int m15 = lane & 15;
    float inv = 1.0f / fmaxf((float)(cnt - 1), 1.0f);
    float4 ad4 = *(const float4*)&ald[(size_t)wid * 4];   // wave-uniform

    float acc[CPL];
#pragma unroll
    for (int k = 0; k < CPL; k++) acc[k] = 0.f;
    const int voff = lane * CPL;   // element offset, loop-invariant

    auto accum_window = [&](int spre, const float* wpre, int cnt8) {
        for (int j = 0; j < cnt8; j += 8) {
            if constexpr (CPL == 8) {
                uint4 pk[8];
                float ww[8];
#pragma unroll
                for (int u = 0; u < 8; u++) {
                    int jj = j + u;
                    int s = READLANE(spre, jj);                 // SGPR
                    ww[u] = __shfl(wpre[jj >> 4], (hpre << 4) | (jj & 15));
                    const unsigned short* rowp = xsb + (size_t)s * HC;  // scalar base
                    pk[u] = *(const uint4*)(rowp + voff);
                }
#pragma unroll
                for (int u = 0; u < 8; u++) {
                    acc[0] += ww[u] * bflo(pk[u].x); acc[1] += ww[u] * bfhi(pk[u].x);
                    acc[2] += ww[u] * bflo(pk[u].y); acc[3] += ww[u] * bfhi(pk[u].y);
                    acc[4] += ww[u] * bflo(pk[u].z); acc[5] += ww[u] * bfhi(pk[u].z);
                    acc[6] += ww[u] * bflo(pk[u].w); acc[7] += ww[u] * bfhi(pk[u].w);
                }
            } else {
                uint2 pk[8];
                float ww[8];
#pragma unroll
                for (int u = 0; u < 8; u++) {
                    int jj = j + u;
                    int s = READLANE(spre, jj);                 // SGPR
                    ww[u] = __shfl(wpre[jj >> 4], (hpre << 4) | (jj & 15));
                    const unsigned short* rowp = xsb + (size_t)s * HC;  // scalar base
                    pk[u] = *(const uint2*)(rowp + voff);
                }
#pragma unroll
                for (int u = 0; u < 8; u++) {
                    acc[0] += ww[u] * bflo(pk[u].x); acc[1] += ww[u] * bfhi(pk[u].x);
                    acc[2] += ww[u] * bflo(pk[u].y); acc[3] += ww[u] * bfhi(pk[u].y);
                }
            }
        }
    };

    if (cnt <= 64) {
        // ---------- fast path: logits + softmax fully in-register ----------
        bool has = (lane < cnt);
        bool isself = (lane == cnt - 1);
        int i = b + lane;
        int s = has ? ssrc[i] : wid;
        float ev[6] = {0.f, 0.f, 0.f, 0.f, 0.f, 0.f};
        if (has) {
            const float* ep = &efc[(size_t)i * 6];
            float2 a0 = *(const float2*)&ep[0];
            float2 a1 = *(const float2*)&ep[2];
            float2 a2 = *(const float2*)&ep[4];
            ev[0] = a0.x; ev[1] = a0.y; ev[2] = a1.x;
            ev[3] = a1.y; ev[4] = a2.x; ev[5] = a2.y;
        }
        float es[6];
#pragma unroll
        for (int k = 0; k < 6; k++) es[k] = ev[k];
#pragma unroll
        for (int off = 32; off; off >>= 1)
#pragma unroll
            for (int k = 0; k < 6; k++) es[k] += __shfl_xor(es[k], off);
        if (has && isself) {
#pragma unroll
            for (int k = 0; k < 6; k++) ev[k] = es[k] * inv;
        }
        float4 as4 = make_float4(0.f, 0.f, 0.f, 0.f);
        if (has) as4 = *(const float4*)&als[(size_t)s * 4];
        float o[4] = {as4.x + ad4.x, as4.y + ad4.y, as4.z + ad4.z, as4.w + ad4.w};
#pragma unroll
        for (int h = 0; h < 4; h++) {
#pragma unroll
            for (int k = 0; k < 6; k++) o[h] += ev[k] * Wea[k * 4 + h];
            o[h] = o[h] > 0.f ? o[h] : 0.2f * o[h];
        }
        float m0 = has ? o[0] : -1e30f, m1 = has ? o[1] : -1e30f;
        float m2 = has ? o[2] : -1e30f, m3 = has ? o[3] : -1e30f;
#pragma unroll
        for (int off = 32; off; off >>= 1) {
            m0 = fmaxf(m0, __shfl_xor(m0, off)); m1 = fmaxf(m1, __shfl_xor(m1, off));
            m2 = fmaxf(m2, __shfl_xor(m2, off)); m3 = fmaxf(m3, __shfl_xor(m3, off));
        }
        float w4[4];
        w4[0] = has ? __expf(o[0] - m0) : 0.f;
        w4[1] = has ? __expf(o[1] - m1) : 0.f;
        w4[2] = has ? __expf(o[2] - m2) : 0.f;
        w4[3] = has ? __expf(o[3] - m3) : 0.f;
        float s0 = w4[0], s1 = w4[1], s2 = w4[2], s3 = w4[3];
#pragma unroll
        for (int off = 32; off; off >>= 1) {
            s0 += __shfl_xor(s0, off); s1 += __shfl_xor(s1, off);
            s2 += __shfl_xor(s2, off); s3 += __shfl_xor(s3, off);
        }
        w4[0] *= 1.f / (s0 + 1e-16f); w4[1] *= 1.f / (s1 + 1e-16f);
        w4[2] *= 1.f / (s2 + 1e-16f); w4[3] *= 1.f / (s3 + 1e-16f);
        float wpre[4];
#pragma unroll
        for (int q = 0; q < 4; q++) {
            int srcl = q * 16 + m15;
            float t0 = __shfl(w4[0], srcl), t1 = __shfl(w4[1], srcl);
            float t2 = __shfl(w4[2], srcl), t3 = __shfl(w4[3], srcl);
            wpre[q] = (hpre == 0) ? t0 : (hpre == 1) ? t1 : (hpre == 2) ? t2 : t3;
        }
        accum_window(s, wpre, (cnt + 7) & ~7);
    } else {
        // ---------- slow path (rare): logits via al scratch ----------
        float es[6] = {0.f, 0.f, 0.f, 0.f, 0.f, 0.f};
        for (int i = b + lane; i < e; i += 64) {
            const float* ep = &efc[(size_t)i * 6];
            float2 a0 = *(const float2*)&ep[0];
            float2 a1 = *(const float2*)&ep[2];
            float2 a2 = *(const float2*)&ep[4];
            es[0] += a0.x; es[1] += a0.y; es[2] += a1.x;
            es[3] += a1.y; es[4] += a2.x; es[5] += a2.y;
        }
#pragma unroll
        for (int off = 32; off; off >>= 1)
#pragma unroll
            for (int k = 0; k < 6; k++) es[k] += __shfl_xor(es[k], off);
        float em[6];
#pragma unroll
        for (int k = 0; k < 6; k++) em[k] = es[k] * inv;

        float m0 = -1e30f, m1 = -1e30f, m2 = -1e30f, m3 = -1e30f;
        for (int i = b + lane; i < e; i += 64) {
            int s = ssrc[i];
            float4 as4 = *(const float4*)&als[(size_t)s * 4];
            float ev[6];
            if (i != e - 1) {
                const float* ep = &efc[(size_t)i * 6];
                float2 a0 = *(const float2*)&ep[0];
                float2 a1 = *(const float2*)&ep[2];
                float2 a2 = *(const float2*)&ep[4];
                ev[0] = a0.x; ev[1] = a0.y; ev[2] = a1.x;
                ev[3] = a1.y; ev[4] = a2.x; ev[5] = a2.y;
            } else {
#pragma unroll
                for (int k = 0; k < 6; k++) ev[k] = em[k];
            }
            float o[4] = {as4.x + ad4.x, as4.y + ad4.y, as4.z + ad4.z, as4.w + ad4.w};
#pragma unroll
            for (int h = 0; h < 4; h++) {
#pragma unroll
                for (int k = 0; k < 6; k++) o[h] += ev[k] * Wea[k * 4 + h];
                o[h] = o[h] > 0.f ? o[h] : 0.2f * o[h];
            }
            *(float4*)&al[(size_t)i * 4] = make_float4(o[0], o[1], o[2], o[3]);
            m0 = fmaxf(m0, o[0]); m1 = fmaxf(m1, o[1]);
            m2 = fmaxf(m2, o[2]); m3 = fmaxf(m3, o[3]);
        }
#pragma unroll
        for (int off = 32; off; off >>= 1) {
            m0 = fmaxf(m0, __shfl_xor(m0, off)); m1 = fmaxf(m1, __shfl_xor(m1, off));
            m2 = fmaxf(m2, __shfl_xor(m2, off)); m3 = fmaxf(m3, __shfl_xor(m3, off));
        }
        float s0 = 0.f, s1 = 0.f, s2 = 0.f, s3 = 0.f;
        for (int i = b + lane; i < e; i += 64) {
            float4 v = *(const float4*)&al[(size_t)i * 4];
            s0 += __expf(v.x - m0); s1 += __expf(v.y - m1);
            s2 += __expf(v.z - m2); s3 += __expf(v.w - m3);
        }
#pragma unroll
        for (int off = 32; off; off >>= 1) {
            s0 += __shfl_xor(s0, off); s1 += __shfl_xor(s1, off);
            s2 += __shfl_xor(s2, off); s3 += __shfl_xor(s3, off);
        }
        float r0 = 1.f / (s0 + 1e-16f), r1 = 1.f / (s1 + 1e-16f);
        float r2 = 1.f / (s2 + 1e-16f), r3 = 1.f / (s3 + 1e-16f);
        float mh = (hpre == 0) ? m0 : (hpre == 1) ? m1 : (hpre == 2) ? m2 : m3;
        float rh = (hpre == 0) ? r0 : (hpre == 1) ? r1 : (hpre == 2) ? r2 : r3;

        for (int base = b; base < e; base += 64) {
            int c = e - base; if (c > 64) c = 64;
            int spre = (base + lane < e) ? ssrc[base + lane] : wid;
            float wpre[4];
#pragma unroll
            for (int q = 0; q < 4; q++) {
                int idx = base + q * 16 + m15;
                wpre[q] = (idx < e) ? __expf(al[(size_t)idx * 4 + hpre] - mh) * rh : 0.f;
            }
            accum_window(spre, wpre, (c + 7) & ~7);
        }
    }

    // ---------- epilogue: bias + BN + ELU + bf16 store ----------
    int base_c = lane * CPL;
    unsigned int opk[CPL / 2];
#pragma unroll
    for (int q = 0; q < CPL / 4; q++) {
        float4 bi = *(const float4*)&bias[base_c + q * 4];
        float4 ga = *(const float4*)&gam[base_c + q * 4];
        float4 be = *(const float4*)&bet[base_c + q * 4];
        float vv[4];
        vv[0] = ga.x * (acc[q * 4 + 0] + bi.x) * RSQ + be.x;
        vv[1] = ga.y * (acc[q * 4 + 1] + bi.y) * RSQ + be.y;
        vv[2] = ga.z * (acc[q * 4 + 2] + bi.z) * RSQ + be.z;
        vv[3] = ga.w * (acc[q * 4 + 3] + bi.w) * RSQ + be.w;
#pragma unroll
        for (int k = 0; k < 4; k++) vv[k] = vv[k] > 0.f ? vv[k] : (__expf(vv[k]) - 1.0f);
        opk[q * 2 + 0] = (unsigned int)f2bf(vv[0]) | ((unsigned int)f2bf(vv[1]) << 16);
        opk[q * 2 + 1] = (unsigned int)f2bf(vv[2]) | ((unsigned int)f2bf(vv[3]) << 16);
    }
    if constexpr (CPL == 4) {
        *(uint2*)&hout[(size_t)wid * HC + base_c] = make_uint2(opk[0], opk[1]);
    } else {
        *(uint4*)&hout[(size_t)wid * HC + base_c] = make_uint4(opk[0], opk[1], opk[2], opk[3]);
    }
}

// ----------------------------------------------------------- pooling + head

__global__ void bounds_kernel(const int* __restrict__ batch, int* __restrict__ first,
                              int* __restrict__ last) {
    int n = blockIdx.x * blockDim.x + threadIdx.x;
    if (n >= NN) return;
    int b = batch[n];
    if (n == 0 || batch[n - 1] != b) first[b] = n;
    if (n == NN - 1 || batch[n + 1] != b) last[b] = n;
}

#define PCHUNK 64
__global__ __launch_bounds__(256) void pool_kernel(const unsigned short* __restrict__ h3,
                                                   const int* __restrict__ batch,
                                                   float* __restrict__ pooled) {
    int c = threadIdx.x;
    int n0 = blockIdx.x * PCHUNK;
    int nend = min(n0 + PCHUNK, NN);
    if (n0 >= NN) return;
    float local = 0.f;
    int curg = batch[n0];
    for (int n = n0; n < nend; n++) {
        int g = batch[n];
        if (g != curg) {
            atomicAdd(&pooled[(size_t)curg * 256 + c], local);
            local = 0.f;
            curg = g;
        }
        local += bf2f(h3[(size_t)n * 256 + c]);
    }
    atomicAdd(&pooled[(size_t)curg * 256 + c], local);
}

__global__ void final_kernel(const float* __restrict__ pooled,
                             const int* __restrict__ first, const int* __restrict__ last,
                             const float* __restrict__ Wf1, const float* __restrict__ bf1,
                             const float* __restrict__ gf, const float* __restrict__ bbf,
                             const float* __restrict__ Wf2, const float* __restrict__ bf2,
                             float* __restrict__ out) {
    int g = blockIdx.x;
    int j = threadIdx.x;  // 32 threads
    __shared__ float hh[32];
    float c = fmaxf((float)(last[g] - first[g] + 1), 1.0f);
    float inv = 1.0f / c;
    float acc = bf1[j];
    for (int i = 0; i < 256; i++) acc += (pooled[(size_t)g * 256 + i] * inv) * Wf1[(size_t)i * 32 + j];
    float v = gf[j] * acc * RSQ + bbf[j];
    hh[j] = v > 0.f ? v : (__expf(v) - 1.0f);
    __syncthreads();
    if (j == 0) {
        float l0 = bf2[0], l1 = bf2[1];
        for (int i = 0; i < 32; i++) {
            l0 += hh[i] * Wf2[i * 2 + 0];
            l1 += hh[i] * Wf2[i * 2 + 1];
        }
        float mx = fmaxf(l0, l1);
        float lse = mx + logf(__expf(l0 - mx) + __expf(l1 - mx));
        out[g * 2 + 0] = l0 - lse;
        out[g * 2 + 1] = l1 - lse;
    }
}

// -------------------------------------------------------------------- launch

extern "C" void kernel_launch(void* const* d_in, const int* in_sizes, int n_in,
                              void* d_out, int out_size, void* d_ws, size_t ws_size,
                              hipStream_t stream) {
    (void)in_sizes; (void)n_in; (void)out_size; (void)ws_size;

    const float* x  = (const float*)d_in[0];
    const float* ef = (const float*)d_in[1];
    const float* W_[3]  = {(const float*)d_in[2],  (const float*)d_in[10], (const float*)d_in[18]};
    const float* We_[3] = {(const float*)d_in[3],  (const float*)d_in[11], (const float*)d_in[19]};
    const float* As_[3] = {(const float*)d_in[4],  (const float*)d_in[12], (const float*)d_in[20]};
    const float* Ad_[3] = {(const float*)d_in[5],  (const float*)d_in[13], (const float*)d_in[21]};
    const float* Ae_[3] = {(const float*)d_in[6],  (const float*)d_in[14], (const float*)d_in[22]};
    const float* Bi_[3] = {(const float*)d_in[7],  (const float*)d_in[15], (const float*)d_in[23]};
    const float* Ga_[3] = {(const float*)d_in[8],  (const float*)d_in[16], (const float*)d_in[24]};
    const float* Be_[3] = {(const float*)d_in[9],  (const float*)d_in[17], (const float*)d_in[25]};
    const float* Wf1 = (const float*)d_in[26];
    const float* bf1 = (const float*)d_in[27];
    const float* gf  = (const float*)d_in[28];
    const float* bbf = (const float*)d_in[29];
    const float* Wf2 = (const float*)d_in[30];
    const float* bf2 = (const float*)d_in[31];
    const int* eidx  = (const int*)d_in[32];
    const int* src0  = eidx;
    const int* dst0  = eidx + EE;
    const int* batch = (const int*)d_in[33];
    float* out = (float*)d_out;

    char* p = (char*)d_ws;
    unsigned short* B0 = (unsigned short*)carve(p, (size_t)NPAD * 512 * 2);
    unsigned short* B2 = (unsigned short*)carve(p, (size_t)NPAD * 512 * 2);
    unsigned short* Xb = (unsigned short*)carve(p, (size_t)NPAD * 512 * 2);
    unsigned short* Wt1 = (unsigned short*)carve(p, (size_t)256 * 64 * 2);
    unsigned short* Wt2 = (unsigned short*)carve(p, (size_t)512 * 256 * 2);
    unsigned short* Wt3 = (unsigned short*)carve(p, (size_t)256 * 512 * 2);
    float* al     = (float*)carve(p, (size_t)ET * 4 * 4);
    float* efc    = (float*)carve(p, (size_t)ET * 6 * 4);
    float* als    = (float*)carve(p, (size_t)NN * 4 * 4);
    float* ald    = (float*)carve(p, (size_t)NN * 4 * 4);
    float* wea    = (float*)carve(p, 3 * 24 * 4);
    float* pooled = (float*)carve(p, (size_t)GG * 256 * 4);
    int* first  = (int*)carve(p, (size_t)GG * 4);
    int* last   = (int*)carve(p, (size_t)GG * 4);
    int* deg    = (int*)carve(p, (size_t)NN * 4);
    int* rowptr = (int*)carve(p, (size_t)(NN + 1) * 4);
    int* epos   = (int*)carve(p, (size_t)EE * 4);
    int* ssrc   = (int*)carve(p, (size_t)ET * 4);
    int* bsum   = (int*)carve(p, 512);

    zero_kernel<<<(NN + GG * 256 + 2 * GG + 255) / 256, 256, 0, stream>>>(deg, pooled, first, last);

    deg_kernel<<<(EE + 255) / 256, 256, 0, stream>>>(dst0, deg, epos);

    int nb = (NN + SCAN_B - 1) / SCAN_B;  // 98
    scan1_kernel<<<nb, SCAN_B, 0, stream>>>(deg, rowptr, bsum, NN);
    scan2_kernel<<<1, 128, 0, stream>>>(bsum, nb);
    scan3_kernel<<<nb, SCAN_B, 0, stream>>>(rowptr, bsum, NN);
    fill_kernel<<<(ET + 255) / 256, 256, 0, stream>>>(src0, dst0, rowptr, epos, deg, ef,
                                                      ssrc, efc);

    prep_kernel<<<(PREP_T + 255) / 256, 256, 0, stream>>>(x, W_[0], W_[1], W_[2],
                                                          We_[0], Ae_[0], We_[1], Ae_[1],
                                                          We_[2], Ae_[2],
                                                          B0, Wt1, Wt2, Wt3, wea);

    int wblocks = (NN * 64 + 255) / 256;
    const int fpad[3] = {64, 256, 512};
    const int HCs[3] = {256, 512, 256};
    const int Cs[3]  = {64, 128, 64};
    const unsigned short* Wts[3] = {Wt1, Wt2, Wt3};
    const unsigned short* inb[3]  = {B0, B2, B0};
    unsigned short* outb[3]       = {B2, B0, B2};

    for (int li = 0; li < 3; li++) {
        int Kp = fpad[li], HC = HCs[li];
        dim3 gg(NPAD / 128, HC / 128);
        if (Cs[li] == 64)
            gemm_fused_kernel<64><<<gg, 256, 0, stream>>>(inb[li], Wts[li], Xb,
                                                          As_[li], Ad_[li], als, ald, Kp);
        else
            gemm_fused_kernel<128><<<gg, 256, 0, stream>>>(inb[li], Wts[li], Xb,
                                                           As_[li], Ad_[li], als, ald, Kp);

        if (Cs[li] == 64)
            aggregate_fused_kernel<64><<<wblocks, 256, 0, stream>>>(
                Xb, rowptr, ssrc, efc, wea + li * 24, als, ald, al,
                Bi_[li], Ga_[li], Be_[li], outb[li]);
        else
            aggregate_fused_kernel<128><<<wblocks, 256, 0, stream>>>(
                Xb, rowptr, ssrc, efc, wea + li * 24, als, ald, al,
                Bi_[li], Ga_[li], Be_[li], outb[li]);
    }

    bounds_kernel<<<(NN + 255) / 256, 256, 0, stream>>>(batch, first, last);
    pool_kernel<<<(NN + PCHUNK - 1) / PCHUNK, 256, 0, stream>>>(B2, batch, pooled);
    final_kernel<<<GG, 32, 0, stream>>>(pooled, first, last, Wf1, bf1, gf, bbf, Wf2, bf2, out);
}

// Round 17
// 413.242 us; speedup vs baseline: 1.1679x; 1.1679x over previous
//
#include <hip/hip_runtime.h>
#include <cstdint>
#include <cstddef>

#define NN 50000
#define NPAD 50048            // 391 * 128
#define EE 800000
#define ET (EE + NN)
#define GG 64
#define HH 4
#define RSQ 0.9999950000374997f   // 1/sqrt(1+1e-5)

typedef short bf16x8 __attribute__((ext_vector_type(8)));
typedef unsigned short u16x8 __attribute__((ext_vector_type(8)));
typedef float f32x4 __attribute__((ext_vector_type(4)));
typedef float f32x2 __attribute__((ext_vector_type(2)));

__device__ __forceinline__ float bf2f(unsigned short u) {
    union { unsigned int i; float f; } v; v.i = ((unsigned int)u) << 16; return v.f;
}
__device__ __forceinline__ unsigned short f2bf(float f) {
    union { float f; unsigned int i; } v; v.f = f;
    unsigned int u = v.i;
    u += 0x7fffu + ((u >> 16) & 1u);
    return (unsigned short)(u >> 16);
}

#if __has_builtin(__builtin_amdgcn_readlane)
#define READLANE(v, l) __builtin_amdgcn_readlane((v), (l))
#else
#define READLANE(v, l) __shfl((v), (l))
#endif

// ---------------------------------------------------------------- fp8 e4m3

#if __has_builtin(__builtin_amdgcn_cvt_pk_fp8_f32) && __has_builtin(__builtin_amdgcn_cvt_pk_f32_fp8)
#define FP8_HW 1
#else
#define FP8_HW 0
#endif

#if !FP8_HW
__device__ __forceinline__ unsigned int enc1_fp8(float f) {
    unsigned int u = __float_as_uint(f);
    unsigned int s = (u >> 24) & 0x80u;
    float a = fabsf(f);
    a = fminf(a, 448.f);
    unsigned int b;
    if (a >= 0.015625f) {
        unsigned int ub = __float_as_uint(a);
        unsigned int mant = ub & 0x7FFFFFu;
        unsigned int keep = mant >> 20;
        unsigned int rem = mant & 0xFFFFFu;
        unsigned int exp = (ub >> 23) - 127u + 7u;
        unsigned int q = (exp << 3) | keep;
        if (rem > 0x80000u || (rem == 0x80000u && (q & 1u))) q++;
        if (q > 0x7Eu) q = 0x7Eu;
        b = q;
    } else {
        int q = (int)(a * 512.0f + 0.5f);
        b = (q > 7) ? 0x08u : (unsigned int)q;
    }
    return s | b;
}
__device__ __forceinline__ float dec1_fp8(unsigned int b) {
    unsigned int sgn = (b & 0x80u) << 24;
    float r;
    if (b & 0x78u) {
        r = __uint_as_float(sgn | (((b & 0x7Fu) + 0x3C0u) << 20));
    } else {
        r = (float)(b & 7u) * 0x1p-9f;
        r = (b & 0x80u) ? -r : r;
    }
    return r;
}
#endif

__device__ __forceinline__ unsigned int pk4_fp8(float f0, float f1, float f2, float f3) {
#if FP8_HW
    int r = __builtin_amdgcn_cvt_pk_fp8_f32(f0, f1, 0, false);
    r = __builtin_amdgcn_cvt_pk_fp8_f32(f2, f3, r, true);
    return (unsigned int)r;
#else
    return enc1_fp8(f0) | (enc1_fp8(f1) << 8) | (enc1_fp8(f2) << 16) | (enc1_fp8(f3) << 24);
#endif
}

__device__ __forceinline__ f32x2 dec2lo_fp8(unsigned int u) {
#if FP8_HW
    return __builtin_amdgcn_cvt_pk_f32_fp8((int)u, false);
#else
    f32x2 r; r[0] = dec1_fp8(u & 0xFFu); r[1] = dec1_fp8((u >> 8) & 0xFFu); return r;
#endif
}
__device__ __forceinline__ f32x2 dec2hi_fp8(unsigned int u) {
#if FP8_HW
    return __builtin_amdgcn_cvt_pk_f32_fp8((int)u, true);
#else
    f32x2 r; r[0] = dec1_fp8((u >> 16) & 0xFFu); r[1] = dec1_fp8(u >> 24); return r;
#endif
}

static inline void* carve(char*& p, size_t bytes) {
    void* r = (void*)p;
    p += (bytes + 255) & ~(size_t)255;
    return r;
}

// ----------------------------------------------------- init (replaces memsets)

__global__ void zero_kernel(int* __restrict__ deg, float* __restrict__ pooled,
                            int* __restrict__ first, int* __restrict__ last) {
    int i = blockIdx.x * blockDim.x + threadIdx.x;
    if (i < NN) deg[i] = 0;
    int j = i - NN;
    if (j >= 0 && j < GG * 256) pooled[j] = 0.f;
    int k = j - GG * 256;
    if (k >= 0 && k < GG) { first[k] = 0; last[k] = -1; }
}

// ------------------------------------------------------------- CSR building

__global__ void deg_kernel(const int* __restrict__ dst0, int* __restrict__ deg,
                           int* __restrict__ epos) {
    int e = blockIdx.x * blockDim.x + threadIdx.x;
    if (e >= EE) return;
    epos[e] = atomicAdd(&deg[dst0[e]], 1);
}

#define SCAN_B 512
__global__ void scan1_kernel(const int* __restrict__ deg, int* __restrict__ out,
                             int* __restrict__ bsum, int n) {
    __shared__ int tmp[SCAN_B];
    int i = blockIdx.x * SCAN_B + threadIdx.x;
    int v = (i < n) ? (deg[i] + 1) : 0;   // +1 self loop
    tmp[threadIdx.x] = v;
    __syncthreads();
    for (int off = 1; off < SCAN_B; off <<= 1) {
        int t = (threadIdx.x >= off) ? tmp[threadIdx.x - off] : 0;
        __syncthreads();
        tmp[threadIdx.x] += t;
        __syncthreads();
    }
    if (i < n) out[i] = tmp[threadIdx.x] - v;       // exclusive
    if (threadIdx.x == SCAN_B - 1) bsum[blockIdx.x] = tmp[threadIdx.x];
}

__global__ void scan2_kernel(int* __restrict__ bsum, int nb) {
    __shared__ int tmp[128];
    int v = (threadIdx.x < nb) ? bsum[threadIdx.x] : 0;
    tmp[threadIdx.x] = v;
    __syncthreads();
    for (int off = 1; off < 128; off <<= 1) {
        int t = (threadIdx.x >= off) ? tmp[threadIdx.x - off] : 0;
        __syncthreads();
        tmp[threadIdx.x] += t;
        __syncthreads();
    }
    if (threadIdx.x < nb) bsum[threadIdx.x] = tmp[threadIdx.x] - v;  // exclusive
}

__global__ void scan3_kernel(int* __restrict__ out, const int* __restrict__ bsum, int n) {
    int i = blockIdx.x * SCAN_B + threadIdx.x;
    if (i < n) out[i] += bsum[blockIdx.x];
    if (i == 0 && blockIdx.x == 0) out[n] = ET;
}

// merged fill: edges then self-loops; also reorders ef into CSR order (efc).
__global__ void fill_kernel(const int* __restrict__ src0, const int* __restrict__ dst0,
                            const int* __restrict__ row_ptr, const int* __restrict__ epos,
                            const int* __restrict__ deg, const float* __restrict__ ef,
                            int* __restrict__ ssrc, float* __restrict__ efc) {
    int e = blockIdx.x * blockDim.x + threadIdx.x;
    if (e < EE) {
        int idx = row_ptr[dst0[e]] + epos[e];
        ssrc[idx] = src0[e];
        const float* s6 = &ef[(size_t)e * 6];
        float* d6 = &efc[(size_t)idx * 6];
        *(float2*)&d6[0] = *(const float2*)&s6[0];
        *(float2*)&d6[2] = *(const float2*)&s6[2];
        *(float2*)&d6[4] = *(const float2*)&s6[4];
    } else if (e < ET) {
        int n = e - EE;
        int idx = row_ptr[n] + deg[n];   // self loop: last slot of the segment
        ssrc[idx] = n;
        float* d6 = &efc[(size_t)idx * 6];
        float2 z = make_float2(0.f, 0.f);
        *(float2*)&d6[0] = z; *(float2*)&d6[2] = z; *(float2*)&d6[4] = z;
    }
}

// -------------------------------------------- prep: convx + convw x3 + wea x3

#define PREP_X  (NPAD * 64)
#define PREP_W1 (PREP_X + 16384)
#define PREP_W2 (PREP_W1 + 131072)
#define PREP_W3 (PREP_W2 + 131072)
#define PREP_T  (PREP_W3 + 128)

__global__ void prep_kernel(const float* __restrict__ x,
                            const float* __restrict__ W1, const float* __restrict__ W2,
                            const float* __restrict__ W3,
                            const float* __restrict__ We1, const float* __restrict__ ae1,
                            const float* __restrict__ We2, const float* __restrict__ ae2,
                            const float* __restrict__ We3, const float* __restrict__ ae3,
                            unsigned short* __restrict__ B0,
                            unsigned short* __restrict__ Wt1, unsigned short* __restrict__ Wt2,
                            unsigned short* __restrict__ Wt3, float* __restrict__ Wea) {
    int i = blockIdx.x * blockDim.x + threadIdx.x;
    if (i < PREP_X) {
        int row = i >> 6, col = i & 63;
        float v = 0.f;
        if (row < NN && col < 32) v = x[(size_t)row * 32 + col];
        B0[i] = f2bf(v);
    } else if (i < PREP_W1) {
        int j = i - PREP_X;
        int c = j >> 6, k = j & 63;
        Wt1[j] = (k < 32) ? f2bf(W1[(size_t)k * 256 + c]) : (unsigned short)0;
    } else if (i < PREP_W2) {
        int j = i - PREP_W1;
        int c = j >> 8, k = j & 255;
        Wt2[j] = f2bf(W2[(size_t)k * 512 + c]);
    } else if (i < PREP_W3) {
        int j = i - PREP_W2;
        int c = j >> 9, k = j & 511;
        Wt3[j] = f2bf(W3[(size_t)k * 256 + c]);
    } else if (i < PREP_T) {
        int t = i - PREP_W3;
        if (t < 72) {
            int l = t / 24, w = t % 24, k = w / 4, h = w % 4;
            const float* We = (l == 0) ? We1 : (l == 1) ? We2 : We3;
            const float* ae = (l == 0) ? ae1 : (l == 1) ? ae2 : ae3;
            int C = (l == 1) ? 128 : 64;
            int HC = 4 * C;
            float s = 0.f;
            for (int c = 0; c < C; c++) s += We[(size_t)k * HC + h * C + c] * ae[(size_t)h * C + c];
            Wea[l * 24 + k * 4 + h] = s;
        }
    }
}

// ------------------------------------------------------------ bf16 MFMA GEMM

#if __has_builtin(__builtin_amdgcn_global_load_lds)
#define GLL_OK 1
#else
#define GLL_OK 0
#endif

#define TILE_LD 136

template <int C_>
__global__ __launch_bounds__(256) void gemm_fused_kernel(const unsigned short* __restrict__ A,
                                                         const unsigned short* __restrict__ Bt,
                                                         unsigned char* __restrict__ X8,
                                                         const float* __restrict__ a_s,
                                                         const float* __restrict__ a_d,
                                                         float* __restrict__ als,
                                                         float* __restrict__ ald,
                                                         int K) {
    constexpr int HC = HH * C_;
    __shared__ unsigned short smem[128 * TILE_LD + 64];
    unsigned short* As = smem;
    unsigned short* Bs = smem + 8192;
    const int tid = threadIdx.x;
    const int bm = blockIdx.x * 128;
    const int bn = blockIdx.y * 128;
    const int lane = tid & 63;
    const int wv = tid >> 6;
    const int wrow = (wv >> 1) * 64;
    const int wcol = (wv & 1) * 64;
    const int l15 = lane & 15;
    const int q = lane >> 4;

    f32x4 acc[4][4];
#pragma unroll
    for (int m = 0; m < 4; m++)
#pragma unroll
        for (int n = 0; n < 4; n++) acc[m][n] = (f32x4)0.f;

    for (int k0 = 0; k0 < K; k0 += 64) {
#pragma unroll
        for (int i = 0; i < 4; i++) {
            int c = (wv * 4 + i) * 64 + lane;
            int row = c >> 3, slot = c & 7;
            int slotG = slot ^ (row & 7);
            const unsigned short* ga = &A[(size_t)(bm + row) * K + k0 + slotG * 8];
            const unsigned short* gb = &Bt[(size_t)(bn + row) * K + k0 + slotG * 8];
#if GLL_OK
            __builtin_amdgcn_global_load_lds(
                (const __attribute__((address_space(1))) unsigned int*)ga,
                (__attribute__((address_space(3))) unsigned int*)&As[(size_t)(wv * 4 + i) * 512],
                16, 0, 0);
            __builtin_amdgcn_global_load_lds(
                (const __attribute__((address_space(1))) unsigned int*)gb,
                (__attribute__((address_space(3))) unsigned int*)&Bs[(size_t)(wv * 4 + i) * 512],
                16, 0, 0);
#else
            *(u16x8*)&As[(size_t)c * 8] = *(const u16x8*)ga;
            *(u16x8*)&Bs[(size_t)c * 8] = *(const u16x8*)gb;
#endif
        }
        __syncthreads();
#pragma unroll
        for (int kk = 0; kk < 2; kk++) {
            bf16x8 af[4], bfr[4];
#pragma unroll
            for (int m = 0; m < 4; m++) {
                int ra = wrow + m * 16 + l15;
                af[m] = *(const bf16x8*)&As[ra * 64 + ((kk * 4 + q) ^ (ra & 7)) * 8];
            }
#pragma unroll
            for (int n = 0; n < 4; n++) {
                int rb = wcol + n * 16 + l15;
                bfr[n] = *(const bf16x8*)&Bs[rb * 64 + ((kk * 4 + q) ^ (rb & 7)) * 8];
            }
#pragma unroll
            for (int m = 0; m < 4; m++)
#pragma unroll
                for (int n = 0; n < 4; n++)
                    acc[m][n] = __builtin_amdgcn_mfma_f32_16x16x32_bf16(af[m], bfr[n], acc[m][n], 0, 0, 0);
        }
        __syncthreads();
    }

    unsigned short* tile = smem;  // reuse; 128 x TILE_LD
#pragma unroll
    for (int m = 0; m < 4; m++) {
#pragma unroll
        for (int n = 0; n < 4; n++) {
#pragma unroll
            for (int j = 0; j < 4; j++) {
                int r = wrow + m * 16 + (lane >> 4) * 4 + j;
                int c = wcol + n * 16 + l15;
                tile[r * TILE_LD + c] = f2bf(acc[m][n][j]);    // m89-verified mapping
            }
        }
    }
    __syncthreads();

    const int tcol = tid & 15;
    const int trow = tid >> 4;
    float as8[8], ad8[8];
#pragma unroll
    for (int k = 0; k < 8; k++) {
        as8[k] = a_s[bn + tcol * 8 + k];
        ad8[k] = a_d[bn + tcol * 8 + k];
    }
#pragma unroll
    for (int i = 0; i < 8; i++) {
        int r = i * 16 + trow;
        int grow = bm + r;
        u16x8 v = *(const u16x8*)&tile[r * TILE_LD + tcol * 8];
        float f[8];
#pragma unroll
        for (int k = 0; k < 8; k++) f[k] = bf2f(v[k]);
        unsigned int r0 = pk4_fp8(f[0], f[1], f[2], f[3]);
        unsigned int r1 = pk4_fp8(f[4], f[5], f[6], f[7]);
        *(uint2*)&X8[(size_t)grow * HC + bn + tcol * 8] = make_uint2(r0, r1);
        float ps = 0.f, pd = 0.f;
#pragma unroll
        for (int k = 0; k < 8; k++) { ps += f[k] * as8[k]; pd += f[k] * ad8[k]; }
        if constexpr (C_ == 64) {
            ps += __shfl_xor(ps, 1); pd += __shfl_xor(pd, 1);
            ps += __shfl_xor(ps, 2); pd += __shfl_xor(pd, 2);
            ps += __shfl_xor(ps, 4); pd += __shfl_xor(pd, 4);
            if ((tid & 7) == 0 && grow < NN) {
                int head = (bn >> 6) + (tcol >> 3);
                als[(size_t)grow * HH + head] = ps;
                ald[(size_t)grow * HH + head] = pd;
            }
        } else {
            ps += __shfl_xor(ps, 1); pd += __shfl_xor(pd, 1);
            ps += __shfl_xor(ps, 2); pd += __shfl_xor(pd, 2);
            ps += __shfl_xor(ps, 4); pd += __shfl_xor(pd, 4);
            ps += __shfl_xor(ps, 8); pd += __shfl_xor(pd, 8);
            if ((tid & 15) == 0 && grow < NN) {
                int head = bn >> 7;
                als[(size_t)grow * HH + head] = ps;
                ald[(size_t)grow * HH + head] = pd;
            }
        }
    }
}

// --- FUSED per-node: emean + logits + leaky + softmax + fp8 aggregation
//     + bias + BN + ELU.  Gather loop: s via READLANE (scalar row base),
//     ww via single shfl broadcast.

template <int C_>
__global__ __launch_bounds__(256) void aggregate_fused_kernel(
        const unsigned char* __restrict__ xs8,
        const int* __restrict__ rowptr, const int* __restrict__ ssrc,
        const float* __restrict__ efc, const float* __restrict__ Wea,
        const float* __restrict__ als, const float* __restrict__ ald,
        float* __restrict__ al,
        const float* __restrict__ bias, const float* __restrict__ gam,
        const float* __restrict__ bet, unsigned short* __restrict__ hout) {
    constexpr int HC = HH * C_;
    constexpr int CPL = HC / 64;   // fp8 bytes/lane: 4 (HC=256) or 8 (HC=512)
    int wid = (blockIdx.x * blockDim.x + threadIdx.x) >> 6;
    int lane = threadIdx.x & 63;
    if (wid >= NN) return;
    int b = rowptr[wid], e = rowptr[wid + 1];
    int cnt = e - b;
    const int hpre = lane >> 4;
    const int m15 = lane & 15;
    float inv = 1.0f / fmaxf((float)(cnt - 1), 1.0f);
    float4 ad4 = *(const float4*)&ald[(size_t)wid * 4];   // wave-uniform

    f32x2 acc2[CPL / 2];
#pragma unroll
    for (int k = 0; k < CPL / 2; k++) acc2[k] = (f32x2)0.f;
    const int voff = lane * CPL;   // loop-invariant per-lane byte offset

    auto accum_window = [&](int spre, const float* wpre, int cnt8) {
        for (int j = 0; j < cnt8; j += 8) {
            if constexpr (CPL == 8) {
                uint2 pk[8];
                float ww[8];
#pragma unroll
                for (int u = 0; u < 8; u++) {
                    int jj = j + u;
                    int s = READLANE(spre, jj);                 // SGPR
                    ww[u] = __shfl(wpre[jj >> 4], (hpre << 4) | (jj & 15));
                    const unsigned char* rowp = xs8 + (size_t)s * HC;  // scalar base
                    pk[u] = *(const uint2*)(rowp + voff);
                }
#pragma unroll
                for (int u = 0; u < 8; u++) {
                    f32x2 wv; wv[0] = ww[u]; wv[1] = ww[u];
                    acc2[0] += wv * dec2lo_fp8(pk[u].x);
                    acc2[1] += wv * dec2hi_fp8(pk[u].x);
                    acc2[2] += wv * dec2lo_fp8(pk[u].y);
                    acc2[3] += wv * dec2hi_fp8(pk[u].y);
                }
            } else {
                unsigned int pk[8];
                float ww[8];
#pragma unroll
                for (int u = 0; u < 8; u++) {
                    int jj = j + u;
                    int s = READLANE(spre, jj);                 // SGPR
                    ww[u] = __shfl(wpre[jj >> 4], (hpre << 4) | (jj & 15));
                    const unsigned char* rowp = xs8 + (size_t)s * HC;  // scalar base
                    pk[u] = *(const unsigned int*)(rowp + voff);
                }
#pragma unroll
                for (int u = 0; u < 8; u++) {
                    f32x2 wv; wv[0] = ww[u]; wv[1] = ww[u];
                    acc2[0] += wv * dec2lo_fp8(pk[u]);
                    acc2[1] += wv * dec2hi_fp8(pk[u]);
                }
            }
        }
    };

    if (cnt <= 64) {
        // ---------- fast path: logits + softmax fully in-register ----------
        bool has = (lane < cnt);
        bool isself = (lane == cnt - 1);
        int i = b + lane;
        int s = has ? ssrc[i] : wid;
        float ev[6] = {0.f, 0.f, 0.f, 0.f, 0.f, 0.f};
        if (has) {
            const float* ep = &efc[(size_t)i * 6];
            float2 a0 = *(const float2*)&ep[0];
            float2 a1 = *(const float2*)&ep[2];
            float2 a2 = *(const float2*)&ep[4];
            ev[0] = a0.x; ev[1] = a0.y; ev[2] = a1.x;
            ev[3] = a1.y; ev[4] = a2.x; ev[5] = a2.y;
        }
        float es[6];
#pragma unroll
        for (int k = 0; k < 6; k++) es[k] = ev[k];
#pragma unroll
        for (int off = 32; off; off >>= 1)
#pragma unroll
            for (int k = 0; k < 6; k++) es[k] += __shfl_xor(es[k], off);
        if (has && isself) {
#pragma unroll
            for (int k = 0; k < 6; k++) ev[k] = es[k] * inv;
        }
        float4 as4 = make_float4(0.f, 0.f, 0.f, 0.f);
        if (has) as4 = *(const float4*)&als[(size_t)s * 4];
        float o[4] = {as4.x + ad4.x, as4.y + ad4.y, as4.z + ad4.z, as4.w + ad4.w};
#pragma unroll
        for (int h = 0; h < 4; h++) {
#pragma unroll
            for (int k = 0; k < 6; k++) o[h] += ev[k] * Wea[k * 4 + h];
            o[h] = o[h] > 0.f ? o[h] : 0.2f * o[h];
        }
        float m0 = has ? o[0] : -1e30f, m1 = has ? o[1] : -1e30f;
        float m2 = has ? o[2] : -1e30f, m3 = has ? o[3] : -1e30f;
#pragma unroll
        for (int off = 32; off; off >>= 1) {
            m0 = fmaxf(m0, __shfl_xor(m0, off)); m1 = fmaxf(m1, __shfl_xor(m1, off));
            m2 = fmaxf(m2, __shfl_xor(m2, off)); m3 = fmaxf(m3, __shfl_xor(m3, off));
        }
        float w4[4];
        w4[0] = has ? __expf(o[0] - m0) : 0.f;
        w4[1] = has ? __expf(o[1] - m1) : 0.f;
        w4[2] = has ? __expf(o[2] - m2) : 0.f;
        w4[3] = has ? __expf(o[3] - m3) : 0.f;
        float s0 = w4[0], s1 = w4[1], s2 = w4[2], s3 = w4[3];
#pragma unroll
        for (int off = 32; off; off >>= 1) {
            s0 += __shfl_xor(s0, off); s1 += __shfl_xor(s1, off);
            s2 += __shfl_xor(s2, off); s3 += __shfl_xor(s3, off);
        }
        w4[0] *= 1.f / (s0 + 1e-16f); w4[1] *= 1.f / (s1 + 1e-16f);
        w4[2] *= 1.f / (s2 + 1e-16f); w4[3] *= 1.f / (s3 + 1e-16f);
        float wpre[4];
#pragma unroll
        for (int q = 0; q < 4; q++) {
            int srcl = q * 16 + m15;
            float t0 = __shfl(w4[0], srcl), t1 = __shfl(w4[1], srcl);
            float t2 = __shfl(w4[2], srcl), t3 = __shfl(w4[3], srcl);
            wpre[q] = (hpre == 0) ? t0 : (hpre == 1) ? t1 : (hpre == 2) ? t2 : t3;
        }
        accum_window(s, wpre, (cnt + 7) & ~7);
    } else {
        // ---------- slow path (rare): logits via al scratch ----------
        float es[6] = {0.f, 0.f, 0.f, 0.f, 0.f, 0.f};
        for (int i = b + lane; i < e; i += 64) {
            const float* ep = &efc[(size_t)i * 6];
            float2 a0 = *(const float2*)&ep[0];
            float2 a1 = *(const float2*)&ep[2];
            float2 a2 = *(const float2*)&ep[4];
            es[0] += a0.x; es[1] += a0.y; es[2] += a1.x;
            es[3] += a1.y; es[4] += a2.x; es[5] += a2.y;
        }
#pragma unroll
        for (int off = 32; off; off >>= 1)
#pragma unroll
            for (int k = 0; k < 6; k++) es[k] += __shfl_xor(es[k], off);
        float em[6];
#pragma unroll
        for (int k = 0; k < 6; k++) em[k] = es[k] * inv;

        float m0 = -1e30f, m1 = -1e30f, m2 = -1e30f, m3 = -1e30f;
        for (int i = b + lane; i < e; i += 64) {
            int s = ssrc[i];
            float4 as4 = *(const float4*)&als[(size_t)s * 4];
            float ev[6];
            if (i != e - 1) {
                const float* ep = &efc[(size_t)i * 6];
                float2 a0 = *(const float2*)&ep[0];
                float2 a1 = *(const float2*)&ep[2];
                float2 a2 = *(const float2*)&ep[4];
                ev[0] = a0.x; ev[1] = a0.y; ev[2] = a1.x;
                ev[3] = a1.y; ev[4] = a2.x; ev[5] = a2.y;
            } else {
#pragma unroll
                for (int k = 0; k < 6; k++) ev[k] = em[k];
            }
            float o[4] = {as4.x + ad4.x, as4.y + ad4.y, as4.z + ad4.z, as4.w + ad4.w};
#pragma unroll
            for (int h = 0; h < 4; h++) {
#pragma unroll
                for (int k = 0; k < 6; k++) o[h] += ev[k] * Wea[k * 4 + h];
                o[h] = o[h] > 0.f ? o[h] : 0.2f * o[h];
            }
            *(float4*)&al[(size_t)i * 4] = make_float4(o[0], o[1], o[2], o[3]);
            m0 = fmaxf(m0, o[0]); m1 = fmaxf(m1, o[1]);
            m2 = fmaxf(m2, o[2]); m3 = fmaxf(m3, o[3]);
        }
#pragma unroll
        for (int off = 32; off; off >>= 1) {
            m0 = fmaxf(m0, __shfl_xor(m0, off)); m1 = fmaxf(m1, __shfl_xor(m1, off));
            m2 = fmaxf(m2, __shfl_xor(m2, off)); m3 = fmaxf(m3, __shfl_xor(m3, off));
        }
        float s0 = 0.f, s1 = 0.f, s2 = 0.f, s3 = 0.f;
        for (int i = b + lane; i < e; i += 64) {
            float4 v = *(const float4*)&al[(size_t)i * 4];
            s0 += __expf(v.x - m0); s1 += __expf(v.y - m1);
            s2 += __expf(v.z - m2); s3 += __expf(v.w - m3);
        }
#pragma unroll
        for (int off = 32; off; off >>= 1) {
            s0 += __shfl_xor(s0, off); s1 += __shfl_xor(s1, off);
            s2 += __shfl_xor(s2, off); s3 += __shfl_xor(s3, off);
        }
        float r0 = 1.f / (s0 + 1e-16f), r1 = 1.f / (s1 + 1e-16f);
        float r2 = 1.f / (s2 + 1e-16f), r3 = 1.f / (s3 + 1e-16f);
        float mh = (hpre == 0) ? m0 : (hpre == 1) ? m1 : (hpre == 2) ? m2 : m3;
        float rh = (hpre == 0) ? r0 : (hpre == 1) ? r1 : (hpre == 2) ? r2 : r3;

        for (int base = b; base < e; base += 64) {
            int c = e - base; if (c > 64) c = 64;
            int spre = (base + lane < e) ? ssrc[base + lane] : wid;
            float wpre[4];
#pragma unroll
            for (int q = 0; q < 4; q++) {
                int idx = base + q * 16 + m15;
                wpre[q] = (idx < e) ? __expf(al[(size_t)idx * 4 + hpre] - mh) * rh : 0.f;
            }
            accum_window(spre, wpre, (c + 7) & ~7);
        }
    }

    // ---------- epilogue: bias + BN + ELU + bf16 store ----------
    float acc[CPL];
#pragma unroll
    for (int k = 0; k < CPL / 2; k++) { acc[2 * k] = acc2[k][0]; acc[2 * k + 1] = acc2[k][1]; }
    int base_c = lane * CPL;
    unsigned int opk[CPL / 2];
#pragma unroll
    for (int q = 0; q < CPL / 4; q++) {
        float4 bi = *(const float4*)&bias[base_c + q * 4];
        float4 ga = *(const float4*)&gam[base_c + q * 4];
        float4 be = *(const float4*)&bet[base_c + q * 4];
        float vv[4];
        vv[0] = ga.x * (acc[q * 4 + 0] + bi.x) * RSQ + be.x;
        vv[1] = ga.y * (acc[q * 4 + 1] + bi.y) * RSQ + be.y;
        vv[2] = ga.z * (acc[q * 4 + 2] + bi.z) * RSQ + be.z;
        vv[3] = ga.w * (acc[q * 4 + 3] + bi.w) * RSQ + be.w;
#pragma unroll
        for (int k = 0; k < 4; k++) vv[k] = vv[k] > 0.f ? vv[k] : (__expf(vv[k]) - 1.0f);
        opk[q * 2 + 0] = (unsigned int)f2bf(vv[0]) | ((unsigned int)f2bf(vv[1]) << 16);
        opk[q * 2 + 1] = (unsigned int)f2bf(vv[2]) | ((unsigned int)f2bf(vv[3]) << 16);
    }
    if constexpr (CPL == 4) {
        *(uint2*)&hout[(size_t)wid * HC + base_c] = make_uint2(opk[0], opk[1]);
    } else {
        *(uint4*)&hout[(size_t)wid * HC + base_c] = make_uint4(opk[0], opk[1], opk[2], opk[3]);
    }
}

// ----------------------------------------------------------- pooling + head

__global__ void bounds_kernel(const int* __restrict__ batch, int* __restrict__ first,
                              int* __restrict__ last) {
    int n = blockIdx.x * blockDim.x + threadIdx.x;
    if (n >= NN) return;
    int b = batch[n];
    if (n == 0 || batch[n - 1] != b) first[b] = n;
    if (n == NN - 1 || batch[n + 1] != b) last[b] = n;
}

#define PCHUNK 64
__global__ __launch_bounds__(256) void pool_kernel(const unsigned short* __restrict__ h3,
                                                   const int* __restrict__ batch,
                                                   float* __restrict__ pooled) {
    int c = threadIdx.x;
    int n0 = blockIdx.x * PCHUNK;
    int nend = min(n0 + PCHUNK, NN);
    if (n0 >= NN) return;
    float local = 0.f;
    int curg = batch[n0];
    for (int n = n0; n < nend; n++) {
        int g = batch[n];
        if (g != curg) {
            atomicAdd(&pooled[(size_t)curg * 256 + c], local);
            local = 0.f;
            curg = g;
        }
        local += bf2f(h3[(size_t)n * 256 + c]);
    }
    atomicAdd(&pooled[(size_t)curg * 256 + c], local);
}

__global__ void final_kernel(const float* __restrict__ pooled,
                             const int* __restrict__ first, const int* __restrict__ last,
                             const float* __restrict__ Wf1, const float* __restrict__ bf1,
                             const float* __restrict__ gf, const float* __restrict__ bbf,
                             const float* __restrict__ Wf2, const float* __restrict__ bf2,
                             float* __restrict__ out) {
    int g = blockIdx.x;
    int j = threadIdx.x;  // 32 threads
    __shared__ float hh[32];
    float c = fmaxf((float)(last[g] - first[g] + 1), 1.0f);
    float inv = 1.0f / c;
    float acc = bf1[j];
    for (int i = 0; i < 256; i++) acc += (pooled[(size_t)g * 256 + i] * inv) * Wf1[(size_t)i * 32 + j];
    float v = gf[j] * acc * RSQ + bbf[j];
    hh[j] = v > 0.f ? v : (__expf(v) - 1.0f);
    __syncthreads();
    if (j == 0) {
        float l0 = bf2[0], l1 = bf2[1];
        for (int i = 0; i < 32; i++) {
            l0 += hh[i] * Wf2[i * 2 + 0];
            l1 += hh[i] * Wf2[i * 2 + 1];
        }
        float mx = fmaxf(l0, l1);
        float lse = mx + logf(__expf(l0 - mx) + __expf(l1 - mx));
        out[g * 2 + 0] = l0 - lse;
        out[g * 2 + 1] = l1 - lse;
    }
}

// -------------------------------------------------------------------- launch

extern "C" void kernel_launch(void* const* d_in, const int* in_sizes, int n_in,
                              void* d_out, int out_size, void* d_ws, size_t ws_size,
                              hipStream_t stream) {
    (void)in_sizes; (void)n_in; (void)out_size; (void)ws_size;

    const float* x  = (const float*)d_in[0];
    const float* ef = (const float*)d_in[1];
    const float* W_[3]  = {(const float*)d_in[2],  (const float*)d_in[10], (const float*)d_in[18]};
    const float* We_[3] = {(const float*)d_in[3],  (const float*)d_in[11], (const float*)d_in[19]};
    const float* As_[3] = {(const float*)d_in[4],  (const float*)d_in[12], (const float*)d_in[20]};
    const float* Ad_[3] = {(const float*)d_in[5],  (const float*)d_in[13], (const float*)d_in[21]};
    const float* Ae_[3] = {(const float*)d_in[6],  (const float*)d_in[14], (const float*)d_in[22]};
    const float* Bi_[3] = {(const float*)d_in[7],  (const float*)d_in[15], (const float*)d_in[23]};
    const float* Ga_[3] = {(const float*)d_in[8],  (const float*)d_in[16], (const float*)d_in[24]};
    const float* Be_[3] = {(const float*)d_in[9],  (const float*)d_in[17], (const float*)d_in[25]};
    const float* Wf1 = (const float*)d_in[26];
    const float* bf1 = (const float*)d_in[27];
    const float* gf  = (const float*)d_in[28];
    const float* bbf = (const float*)d_in[29];
    const float* Wf2 = (const float*)d_in[30];
    const float* bf2 = (const float*)d_in[31];
    const int* eidx  = (const int*)d_in[32];
    const int* src0  = eidx;
    const int* dst0  = eidx + EE;
    const int* batch = (const int*)d_in[33];
    float* out = (float*)d_out;

    char* p = (char*)d_ws;
    unsigned short* B0 = (unsigned short*)carve(p, (size_t)NPAD * 512 * 2);
    unsigned short* B2 = (unsigned short*)carve(p, (size_t)NPAD * 512 * 2);
    unsigned char*  X8 = (unsigned char*)carve(p, (size_t)NPAD * 512);
    unsigned short* Wt1 = (unsigned short*)carve(p, (size_t)256 * 64 * 2);
    unsigned short* Wt2 = (unsigned short*)carve(p, (size_t)512 * 256 * 2);
    unsigned short* Wt3 = (unsigned short*)carve(p, (size_t)256 * 512 * 2);
    float* al     = (float*)carve(p, (size_t)ET * 4 * 4);
    float* efc    = (float*)carve(p, (size_t)ET * 6 * 4);
    float* als    = (float*)carve(p, (size_t)NN * 4 * 4);
    float* ald    = (float*)carve(p, (size_t)NN * 4 * 4);
    float* wea    = (float*)carve(p, 3 * 24 * 4);
    float* pooled = (float*)carve(p, (size_t)GG * 256 * 4);
    int* first  = (int*)carve(p, (size_t)GG * 4);
    int* last   = (int*)carve(p, (size_t)GG * 4);
    int* deg    = (int*)carve(p, (size_t)NN * 4);
    int* rowptr = (int*)carve(p, (size_t)(NN + 1) * 4);
    int* epos   = (int*)carve(p, (size_t)EE * 4);
    int* ssrc   = (int*)carve(p, (size_t)ET * 4);
    int* bsum   = (int*)carve(p, 512);

    zero_kernel<<<(NN + GG * 256 + 2 * GG + 255) / 256, 256, 0, stream>>>(deg, pooled, first, last);

    deg_kernel<<<(EE + 255) / 256, 256, 0, stream>>>(dst0, deg, epos);

    int nb = (NN + SCAN_B - 1) / SCAN_B;  // 98
    scan1_kernel<<<nb, SCAN_B, 0, stream>>>(deg, rowptr, bsum, NN);
    scan2_kernel<<<1, 128, 0, stream>>>(bsum, nb);
    scan3_kernel<<<nb, SCAN_B, 0, stream>>>(rowptr, bsum, NN);
    fill_kernel<<<(ET + 255) / 256, 256, 0, stream>>>(src0, dst0, rowptr, epos, deg, ef,
                                                      ssrc, efc);

    prep_kernel<<<(PREP_T + 255) / 256, 256, 0, stream>>>(x, W_[0], W_[1], W_[2],
                                                          We_[0], Ae_[0], We_[1], Ae_[1],
                                                          We_[2], Ae_[2],
                                                          B0, Wt1, Wt2, Wt3, wea);

    int wblocks = (NN * 64 + 255) / 256;
    const int fpad[3] = {64, 256, 512};
    const int HCs[3] = {256, 512, 256};
    const int Cs[3]  = {64, 128, 64};
    const unsigned short* Wts[3] = {Wt1, Wt2, Wt3};
    const unsigned short* inb[3]  = {B0, B2, B0};
    unsigned short* outb[3]       = {B2, B0, B2};

    for (int li = 0; li < 3; li++) {
        int Kp = fpad[li], HC = HCs[li];
        dim3 gg(NPAD / 128, HC / 128);
        if (Cs[li] == 64)
            gemm_fused_kernel<64><<<gg, 256, 0, stream>>>(inb[li], Wts[li], X8,
                                                          As_[li], Ad_[li], als, ald, Kp);
        else
            gemm_fused_kernel<128><<<gg, 256, 0, stream>>>(inb[li], Wts[li], X8,
                                                           As_[li], Ad_[li], als, ald, Kp);

        if (Cs[li] == 64)
            aggregate_fused_kernel<64><<<wblocks, 256, 0, stream>>>(
                X8, rowptr, ssrc, efc, wea + li * 24, als, ald, al,
                Bi_[li], Ga_[li], Be_[li], outb[li]);
        else
            aggregate_fused_kernel<128><<<wblocks, 256, 0, stream>>>(
                X8, rowptr, ssrc, efc, wea + li * 24, als, ald, al,
                Bi_[li], Ga_[li], Be_[li], outb[li]);
    }

    bounds_kernel<<<(NN + 255) / 256, 256, 0, stream>>>(batch, first, last);
    pool_kernel<<<(NN + PCHUNK - 1) / PCHUNK, 256, 0, stream>>>(B2, batch, pooled);
    final_kernel<<<GG, 32, 0, stream>>>(pooled, first, last, Wf1, bf1, gf, bbf, Wf2, bf2, out);
}

// Round 18
// 412.828 us; speedup vs baseline: 1.1691x; 1.0010x over previous
//
#include <hip/hip_runtime.h>
#include <cstdint>
#include <cstddef>

#define NN 50000
#define NPAD 50048            // 391 * 128
#define EE 800000
#define ET (EE + NN)
#define GG 64
#define HH 4
#define RSQ 0.9999950000374997f   // 1/sqrt(1+1e-5)

typedef short bf16x8 __attribute__((ext_vector_type(8)));
typedef unsigned short u16x8 __attribute__((ext_vector_type(8)));
typedef float f32x4 __attribute__((ext_vector_type(4)));
typedef float f32x2 __attribute__((ext_vector_type(2)));

__device__ __forceinline__ float bf2f(unsigned short u) {
    union { unsigned int i; float f; } v; v.i = ((unsigned int)u) << 16; return v.f;
}
__device__ __forceinline__ unsigned short f2bf(float f) {
    union { float f; unsigned int i; } v; v.f = f;
    unsigned int u = v.i;
    u += 0x7fffu + ((u >> 16) & 1u);
    return (unsigned short)(u >> 16);
}

#if __has_builtin(__builtin_amdgcn_readlane)
#define READLANE(v, l) __builtin_amdgcn_readlane((v), (l))
#else
#define READLANE(v, l) __shfl((v), (l))
#endif

// ---------------------------------------------------------------- fp8 e4m3

#if __has_builtin(__builtin_amdgcn_cvt_pk_fp8_f32) && __has_builtin(__builtin_amdgcn_cvt_pk_f32_fp8)
#define FP8_HW 1
#else
#define FP8_HW 0
#endif

#if !FP8_HW
__device__ __forceinline__ unsigned int enc1_fp8(float f) {
    unsigned int u = __float_as_uint(f);
    unsigned int s = (u >> 24) & 0x80u;
    float a = fabsf(f);
    a = fminf(a, 448.f);
    unsigned int b;
    if (a >= 0.015625f) {
        unsigned int ub = __float_as_uint(a);
        unsigned int mant = ub & 0x7FFFFFu;
        unsigned int keep = mant >> 20;
        unsigned int rem = mant & 0xFFFFFu;
        unsigned int exp = (ub >> 23) - 127u + 7u;
        unsigned int q = (exp << 3) | keep;
        if (rem > 0x80000u || (rem == 0x80000u && (q & 1u))) q++;
        if (q > 0x7Eu) q = 0x7Eu;
        b = q;
    } else {
        int q = (int)(a * 512.0f + 0.5f);
        b = (q > 7) ? 0x08u : (unsigned int)q;
    }
    return s | b;
}
__device__ __forceinline__ float dec1_fp8(unsigned int b) {
    unsigned int sgn = (b & 0x80u) << 24;
    float r;
    if (b & 0x78u) {
        r = __uint_as_float(sgn | (((b & 0x7Fu) + 0x3C0u) << 20));
    } else {
        r = (float)(b & 7u) * 0x1p-9f;
        r = (b & 0x80u) ? -r : r;
    }
    return r;
}
#endif

__device__ __forceinline__ unsigned int pk4_fp8(float f0, float f1, float f2, float f3) {
#if FP8_HW
    int r = __builtin_amdgcn_cvt_pk_fp8_f32(f0, f1, 0, false);
    r = __builtin_amdgcn_cvt_pk_fp8_f32(f2, f3, r, true);
    return (unsigned int)r;
#else
    return enc1_fp8(f0) | (enc1_fp8(f1) << 8) | (enc1_fp8(f2) << 16) | (enc1_fp8(f3) << 24);
#endif
}

__device__ __forceinline__ f32x2 dec2lo_fp8(unsigned int u) {
#if FP8_HW
    return __builtin_amdgcn_cvt_pk_f32_fp8((int)u, false);
#else
    f32x2 r; r[0] = dec1_fp8(u & 0xFFu); r[1] = dec1_fp8((u >> 8) & 0xFFu); return r;
#endif
}
__device__ __forceinline__ f32x2 dec2hi_fp8(unsigned int u) {
#if FP8_HW
    return __builtin_amdgcn_cvt_pk_f32_fp8((int)u, true);
#else
    f32x2 r; r[0] = dec1_fp8((u >> 16) & 0xFFu); r[1] = dec1_fp8(u >> 24); return r;
#endif
}

static inline void* carve(char*& p, size_t bytes) {
    void* r = (void*)p;
    p += (bytes + 255) & ~(size_t)255;
    return r;
}

// ----------------------------------------------------- init (replaces memsets)

__global__ void zero_kernel(int* __restrict__ deg, float* __restrict__ pooled,
                            int* __restrict__ first, int* __restrict__ last) {
    int i = blockIdx.x * blockDim.x + threadIdx.x;
    if (i < NN) deg[i] = 0;
    int j = i - NN;
    if (j >= 0 && j < GG * 256) pooled[j] = 0.f;
    int k = j - GG * 256;
    if (k >= 0 && k < GG) { first[k] = 0; last[k] = -1; }
}

// ------------------------------------------------------------- CSR building

__global__ void deg_kernel(const int* __restrict__ dst0, int* __restrict__ deg,
                           int* __restrict__ epos) {
    int e = blockIdx.x * blockDim.x + threadIdx.x;
    if (e >= EE) return;
    epos[e] = atomicAdd(&deg[dst0[e]], 1);
}

#define SCAN_B 512
__global__ void scan1_kernel(const int* __restrict__ deg, int* __restrict__ out,
                             int* __restrict__ bsum, int n) {
    __shared__ int tmp[SCAN_B];
    int i = blockIdx.x * SCAN_B + threadIdx.x;
    int v = (i < n) ? (deg[i] + 1) : 0;   // +1 self loop
    tmp[threadIdx.x] = v;
    __syncthreads();
    for (int off = 1; off < SCAN_B; off <<= 1) {
        int t = (threadIdx.x >= off) ? tmp[threadIdx.x - off] : 0;
        __syncthreads();
        tmp[threadIdx.x] += t;
        __syncthreads();
    }
    if (i < n) out[i] = tmp[threadIdx.x] - v;       // exclusive
    if (threadIdx.x == SCAN_B - 1) bsum[blockIdx.x] = tmp[threadIdx.x];
}

__global__ void scan2_kernel(int* __restrict__ bsum, int nb) {
    __shared__ int tmp[128];
    int v = (threadIdx.x < nb) ? bsum[threadIdx.x] : 0;
    tmp[threadIdx.x] = v;
    __syncthreads();
    for (int off = 1; off < 128; off <<= 1) {
        int t = (threadIdx.x >= off) ? tmp[threadIdx.x - off] : 0;
        __syncthreads();
        tmp[threadIdx.x] += t;
        __syncthreads();
    }
    if (threadIdx.x < nb) bsum[threadIdx.x] = tmp[threadIdx.x] - v;  // exclusive
}

__global__ void scan3_kernel(int* __restrict__ out, const int* __restrict__ bsum, int n) {
    int i = blockIdx.x * SCAN_B + threadIdx.x;
    if (i < n) out[i] += bsum[blockIdx.x];
    if (i == 0 && blockIdx.x == 0) out[n] = ET;
}

// merged fill: edges then self-loops; also reorders ef into CSR order (efc).
__global__ void fill_kernel(const int* __restrict__ src0, const int* __restrict__ dst0,
                            const int* __restrict__ row_ptr, const int* __restrict__ epos,
                            const int* __restrict__ deg, const float* __restrict__ ef,
                            int* __restrict__ ssrc, float* __restrict__ efc) {
    int e = blockIdx.x * blockDim.x + threadIdx.x;
    if (e < EE) {
        int idx = row_ptr[dst0[e]] + epos[e];
        ssrc[idx] = src0[e];
        const float* s6 = &ef[(size_t)e * 6];
        float* d6 = &efc[(size_t)idx * 6];
        *(float2*)&d6[0] = *(const float2*)&s6[0];
        *(float2*)&d6[2] = *(const float2*)&s6[2];
        *(float2*)&d6[4] = *(const float2*)&s6[4];
    } else if (e < ET) {
        int n = e - EE;
        int idx = row_ptr[n] + deg[n];   // self loop: last slot of the segment
        ssrc[idx] = n;
        float* d6 = &efc[(size_t)idx * 6];
        float2 z = make_float2(0.f, 0.f);
        *(float2*)&d6[0] = z; *(float2*)&d6[2] = z; *(float2*)&d6[4] = z;
    }
}

// -------------------------------------------- prep: convx + convw x3 + wea x3

#define PREP_X  (NPAD * 64)
#define PREP_W1 (PREP_X + 16384)
#define PREP_W2 (PREP_W1 + 131072)
#define PREP_W3 (PREP_W2 + 131072)
#define PREP_T  (PREP_W3 + 128)

__global__ void prep_kernel(const float* __restrict__ x,
                            const float* __restrict__ W1, const float* __restrict__ W2,
                            const float* __restrict__ W3,
                            const float* __restrict__ We1, const float* __restrict__ ae1,
                            const float* __restrict__ We2, const float* __restrict__ ae2,
                            const float* __restrict__ We3, const float* __restrict__ ae3,
                            unsigned short* __restrict__ B0,
                            unsigned short* __restrict__ Wt1, unsigned short* __restrict__ Wt2,
                            unsigned short* __restrict__ Wt3, float* __restrict__ Wea) {
    int i = blockIdx.x * blockDim.x + threadIdx.x;
    if (i < PREP_X) {
        int row = i >> 6, col = i & 63;
        float v = 0.f;
        if (row < NN && col < 32) v = x[(size_t)row * 32 + col];
        B0[i] = f2bf(v);
    } else if (i < PREP_W1) {
        int j = i - PREP_X;
        int c = j >> 6, k = j & 63;
        Wt1[j] = (k < 32) ? f2bf(W1[(size_t)k * 256 + c]) : (unsigned short)0;
    } else if (i < PREP_W2) {
        int j = i - PREP_W1;
        int c = j >> 8, k = j & 255;
        Wt2[j] = f2bf(W2[(size_t)k * 512 + c]);
    } else if (i < PREP_W3) {
        int j = i - PREP_W2;
        int c = j >> 9, k = j & 511;
        Wt3[j] = f2bf(W3[(size_t)k * 256 + c]);
    } else if (i < PREP_T) {
        int t = i - PREP_W3;
        if (t < 72) {
            int l = t / 24, w = t % 24, k = w / 4, h = w % 4;
            const float* We = (l == 0) ? We1 : (l == 1) ? We2 : We3;
            const float* ae = (l == 0) ? ae1 : (l == 1) ? ae2 : ae3;
            int C = (l == 1) ? 128 : 64;
            int HC = 4 * C;
            float s = 0.f;
            for (int c = 0; c < C; c++) s += We[(size_t)k * HC + h * C + c] * ae[(size_t)h * C + c];
            Wea[l * 24 + k * 4 + h] = s;
        }
    }
}

// ------------------------------------------------------------ bf16 MFMA GEMM

#if __has_builtin(__builtin_amdgcn_global_load_lds)
#define GLL_OK 1
#else
#define GLL_OK 0
#endif

#define TILE_LD 136

template <int C_>
__global__ __launch_bounds__(256) void gemm_fused_kernel(const unsigned short* __restrict__ A,
                                                         const unsigned short* __restrict__ Bt,
                                                         unsigned char* __restrict__ X8,
                                                         const float* __restrict__ a_s,
                                                         const float* __restrict__ a_d,
                                                         float* __restrict__ als,
                                                         float* __restrict__ ald,
                                                         int K) {
    constexpr int HC = HH * C_;
    __shared__ unsigned short smem[128 * TILE_LD + 64];
    unsigned short* As = smem;
    unsigned short* Bs = smem + 8192;
    const int tid = threadIdx.x;
    const int bm = blockIdx.x * 128;
    const int bn = blockIdx.y * 128;
    const int lane = tid & 63;
    const int wv = tid >> 6;
    const int wrow = (wv >> 1) * 64;
    const int wcol = (wv & 1) * 64;
    const int l15 = lane & 15;
    const int q = lane >> 4;

    f32x4 acc[4][4];
#pragma unroll
    for (int m = 0; m < 4; m++)
#pragma unroll
        for (int n = 0; n < 4; n++) acc[m][n] = (f32x4)0.f;

    for (int k0 = 0; k0 < K; k0 += 64) {
#pragma unroll
        for (int i = 0; i < 4; i++) {
            int c = (wv * 4 + i) * 64 + lane;
            int row = c >> 3, slot = c & 7;
            int slotG = slot ^ (row & 7);
            const unsigned short* ga = &A[(size_t)(bm + row) * K + k0 + slotG * 8];
            const unsigned short* gb = &Bt[(size_t)(bn + row) * K + k0 + slotG * 8];
#if GLL_OK
            __builtin_amdgcn_global_load_lds(
                (const __attribute__((address_space(1))) unsigned int*)ga,
                (__attribute__((address_space(3))) unsigned int*)&As[(size_t)(wv * 4 + i) * 512],
                16, 0, 0);
            __builtin_amdgcn_global_load_lds(
                (const __attribute__((address_space(1))) unsigned int*)gb,
                (__attribute__((address_space(3))) unsigned int*)&Bs[(size_t)(wv * 4 + i) * 512],
                16, 0, 0);
#else
            *(u16x8*)&As[(size_t)c * 8] = *(const u16x8*)ga;
            *(u16x8*)&Bs[(size_t)c * 8] = *(const u16x8*)gb;
#endif
        }
        __syncthreads();
#pragma unroll
        for (int kk = 0; kk < 2; kk++) {
            bf16x8 af[4], bfr[4];
#pragma unroll
            for (int m = 0; m < 4; m++) {
                int ra = wrow + m * 16 + l15;
                af[m] = *(const bf16x8*)&As[ra * 64 + ((kk * 4 + q) ^ (ra & 7)) * 8];
            }
#pragma unroll
            for (int n = 0; n < 4; n++) {
                int rb = wcol + n * 16 + l15;
                bfr[n] = *(const bf16x8*)&Bs[rb * 64 + ((kk * 4 + q) ^ (rb & 7)) * 8];
            }
#pragma unroll
            for (int m = 0; m < 4; m++)
#pragma unroll
                for (int n = 0; n < 4; n++)
                    acc[m][n] = __builtin_amdgcn_mfma_f32_16x16x32_bf16(af[m], bfr[n], acc[m][n], 0, 0, 0);
        }
        __syncthreads();
    }

    unsigned short* tile = smem;  // reuse; 128 x TILE_LD
#pragma unroll
    for (int m = 0; m < 4; m++) {
#pragma unroll
        for (int n = 0; n < 4; n++) {
#pragma unroll
            for (int j = 0; j < 4; j++) {
                int r = wrow + m * 16 + (lane >> 4) * 4 + j;
                int c = wcol + n * 16 + l15;
                tile[r * TILE_LD + c] = f2bf(acc[m][n][j]);    // m89-verified mapping
            }
        }
    }
    __syncthreads();

    const int tcol = tid & 15;
    const int trow = tid >> 4;
    float as8[8], ad8[8];
#pragma unroll
    for (int k = 0; k < 8; k++) {
        as8[k] = a_s[bn + tcol * 8 + k];
        ad8[k] = a_d[bn + tcol * 8 + k];
    }
#pragma unroll
    for (int i = 0; i < 8; i++) {
        int r = i * 16 + trow;
        int grow = bm + r;
        u16x8 v = *(const u16x8*)&tile[r * TILE_LD + tcol * 8];
        float f[8];
#pragma unroll
        for (int k = 0; k < 8; k++) f[k] = bf2f(v[k]);
        unsigned int r0 = pk4_fp8(f[0], f[1], f[2], f[3]);
        unsigned int r1 = pk4_fp8(f[4], f[5], f[6], f[7]);
        *(uint2*)&X8[(size_t)grow * HC + bn + tcol * 8] = make_uint2(r0, r1);
        float ps = 0.f, pd = 0.f;
#pragma unroll
        for (int k = 0; k < 8; k++) { ps += f[k] * as8[k]; pd += f[k] * ad8[k]; }
        if constexpr (C_ == 64) {
            ps += __shfl_xor(ps, 1); pd += __shfl_xor(pd, 1);
            ps += __shfl_xor(ps, 2); pd += __shfl_xor(pd, 2);
            ps += __shfl_xor(ps, 4); pd += __shfl_xor(pd, 4);
            if ((tid & 7) == 0 && grow < NN) {
                int head = (bn >> 6) + (tcol >> 3);
                als[(size_t)grow * HH + head] = ps;
                ald[(size_t)grow * HH + head] = pd;
            }
        } else {
            ps += __shfl_xor(ps, 1); pd += __shfl_xor(pd, 1);
            ps += __shfl_xor(ps, 2); pd += __shfl_xor(pd, 2);
            ps += __shfl_xor(ps, 4); pd += __shfl_xor(pd, 4);
            ps += __shfl_xor(ps, 8); pd += __shfl_xor(pd, 8);
            if ((tid & 15) == 0 && grow < NN) {
                int head = bn >> 7;
                als[(size_t)grow * HH + head] = ps;
                ald[(size_t)grow * HH + head] = pd;
            }
        }
    }
}

// --- FUSED per-node: emean + logits + leaky + softmax + fp8 aggregation
//     + bias + BN + ELU.  ONE WAVE PER BLOCK (grid = NN) so retired waves
//     are backfilled immediately — no block-quorum tail from degree variance.

template <int C_>
__global__ __launch_bounds__(64) void aggregate_fused_kernel(
        const unsigned char* __restrict__ xs8,
        const int* __restrict__ rowptr, const int* __restrict__ ssrc,
        const float* __restrict__ efc, const float* __restrict__ Wea,
        const float* __restrict__ als, const float* __restrict__ ald,
        float* __restrict__ al,
        const float* __restrict__ bias, const float* __restrict__ gam,
        const float* __restrict__ bet, unsigned short* __restrict__ hout) {
    constexpr int HC = HH * C_;
    constexpr int CPL = HC / 64;   // fp8 bytes/lane: 4 (HC=256) or 8 (HC=512)
    int wid = blockIdx.x;
    int lane = threadIdx.x & 63;
    if (wid >= NN) return;
    int b = rowptr[wid], e = rowptr[wid + 1];
    int cnt = e - b;
    const int hpre = lane >> 4;
    const int m15 = lane & 15;
    float inv = 1.0f / fmaxf((float)(cnt - 1), 1.0f);
    float4 ad4 = *(const float4*)&ald[(size_t)wid * 4];   // wave-uniform

    f32x2 acc2[CPL / 2];
#pragma unroll
    for (int k = 0; k < CPL / 2; k++) acc2[k] = (f32x2)0.f;
    const int voff = lane * CPL;   // loop-invariant per-lane byte offset

    auto accum_window = [&](int spre, const float* wpre, int cnt8) {
        for (int j = 0; j < cnt8; j += 8) {
            if constexpr (CPL == 8) {
                uint2 pk[8];
                float ww[8];
#pragma unroll
                for (int u = 0; u < 8; u++) {
                    int jj = j + u;
                    int s = READLANE(spre, jj);                 // SGPR
                    ww[u] = __shfl(wpre[jj >> 4], (hpre << 4) | (jj & 15));
                    const unsigned char* rowp = xs8 + (size_t)s * HC;  // scalar base
                    pk[u] = *(const uint2*)(rowp + voff);
                }
#pragma unroll
                for (int u = 0; u < 8; u++) {
                    f32x2 wv; wv[0] = ww[u]; wv[1] = ww[u];
                    acc2[0] += wv * dec2lo_fp8(pk[u].x);
                    acc2[1] += wv * dec2hi_fp8(pk[u].x);
                    acc2[2] += wv * dec2lo_fp8(pk[u].y);
                    acc2[3] += wv * dec2hi_fp8(pk[u].y);
                }
            } else {
                unsigned int pk[8];
                float ww[8];
#pragma unroll
                for (int u = 0; u < 8; u++) {
                    int jj = j + u;
                    int s = READLANE(spre, jj);                 // SGPR
                    ww[u] = __shfl(wpre[jj >> 4], (hpre << 4) | (jj & 15));
                    const unsigned char* rowp = xs8 + (size_t)s * HC;  // scalar base
                    pk[u] = *(const unsigned int*)(rowp + voff);
                }
#pragma unroll
                for (int u = 0; u < 8; u++) {
                    f32x2 wv; wv[0] = ww[u]; wv[1] = ww[u];
                    acc2[0] += wv * dec2lo_fp8(pk[u]);
                    acc2[1] += wv * dec2hi_fp8(pk[u]);
                }
            }
        }
    };

    if (cnt <= 64) {
        // ---------- fast path: logits + softmax fully in-register ----------
        bool has = (lane < cnt);
        bool isself = (lane == cnt - 1);
        int i = b + lane;
        int s = has ? ssrc[i] : wid;
        float ev[6] = {0.f, 0.f, 0.f, 0.f, 0.f, 0.f};
        if (has) {
            const float* ep = &efc[(size_t)i * 6];
            float2 a0 = *(const float2*)&ep[0];
            float2 a1 = *(const float2*)&ep[2];
            float2 a2 = *(const float2*)&ep[4];
            ev[0] = a0.x; ev[1] = a0.y; ev[2] = a1.x;
            ev[3] = a1.y; ev[4] = a2.x; ev[5] = a2.y;
        }
        float es[6];
#pragma unroll
        for (int k = 0; k < 6; k++) es[k] = ev[k];
#pragma unroll
        for (int off = 32; off; off >>= 1)
#pragma unroll
            for (int k = 0; k < 6; k++) es[k] += __shfl_xor(es[k], off);
        if (has && isself) {
#pragma unroll
            for (int k = 0; k < 6; k++) ev[k] = es[k] * inv;
        }
        float4 as4 = make_float4(0.f, 0.f, 0.f, 0.f);
        if (has) as4 = *(const float4*)&als[(size_t)s * 4];
        float o[4] = {as4.x + ad4.x, as4.y + ad4.y, as4.z + ad4.z, as4.w + ad4.w};
#pragma unroll
        for (int h = 0; h < 4; h++) {
#pragma unroll
            for (int k = 0; k < 6; k++) o[h] += ev[k] * Wea[k * 4 + h];
            o[h] = o[h] > 0.f ? o[h] : 0.2f * o[h];
        }
        float m0 = has ? o[0] : -1e30f, m1 = has ? o[1] : -1e30f;
        float m2 = has ? o[2] : -1e30f, m3 = has ? o[3] : -1e30f;
#pragma unroll
        for (int off = 32; off; off >>= 1) {
            m0 = fmaxf(m0, __shfl_xor(m0, off)); m1 = fmaxf(m1, __shfl_xor(m1, off));
            m2 = fmaxf(m2, __shfl_xor(m2, off)); m3 = fmaxf(m3, __shfl_xor(m3, off));
        }
        float w4[4];
        w4[0] = has ? __expf(o[0] - m0) : 0.f;
        w4[1] = has ? __expf(o[1] - m1) : 0.f;
        w4[2] = has ? __expf(o[2] - m2) : 0.f;
        w4[3] = has ? __expf(o[3] - m3) : 0.f;
        float s0 = w4[0], s1 = w4[1], s2 = w4[2], s3 = w4[3];
#pragma unroll
        for (int off = 32; off; off >>= 1) {
            s0 += __shfl_xor(s0, off); s1 += __shfl_xor(s1, off);
            s2 += __shfl_xor(s2, off); s3 += __shfl_xor(s3, off);
        }
        w4[0] *= 1.f / (s0 + 1e-16f); w4[1] *= 1.f / (s1 + 1e-16f);
        w4[2] *= 1.f / (s2 + 1e-16f); w4[3] *= 1.f / (s3 + 1e-16f);
        float wpre[4];
#pragma unroll
        for (int q = 0; q < 4; q++) {
            int srcl = q * 16 + m15;
            float t0 = __shfl(w4[0], srcl), t1 = __shfl(w4[1], srcl);
            float t2 = __shfl(w4[2], srcl), t3 = __shfl(w4[3], srcl);
            wpre[q] = (hpre == 0) ? t0 : (hpre == 1) ? t1 : (hpre == 2) ? t2 : t3;
        }
        accum_window(s, wpre, (cnt + 7) & ~7);
    } else {
        // ---------- slow path (rare): logits via al scratch ----------
        float es[6] = {0.f, 0.f, 0.f, 0.f, 0.f, 0.f};
        for (int i = b + lane; i < e; i += 64) {
            const float* ep = &efc[(size_t)i * 6];
            float2 a0 = *(const float2*)&ep[0];
            float2 a1 = *(const float2*)&ep[2];
            float2 a2 = *(const float2*)&ep[4];
            es[0] += a0.x; es[1] += a0.y; es[2] += a1.x;
            es[3] += a1.y; es[4] += a2.x; es[5] += a2.y;
        }
#pragma unroll
        for (int off = 32; off; off >>= 1)
#pragma unroll
            for (int k = 0; k < 6; k++) es[k] += __shfl_xor(es[k], off);
        float em[6];
#pragma unroll
        for (int k = 0; k < 6; k++) em[k] = es[k] * inv;

        float m0 = -1e30f, m1 = -1e30f, m2 = -1e30f, m3 = -1e30f;
        for (int i = b + lane; i < e; i += 64) {
            int s = ssrc[i];
            float4 as4 = *(const float4*)&als[(size_t)s * 4];
            float ev[6];
            if (i != e - 1) {
                const float* ep = &efc[(size_t)i * 6];
                float2 a0 = *(const float2*)&ep[0];
                float2 a1 = *(const float2*)&ep[2];
                float2 a2 = *(const float2*)&ep[4];
                ev[0] = a0.x; ev[1] = a0.y; ev[2] = a1.x;
                ev[3] = a1.y; ev[4] = a2.x; ev[5] = a2.y;
            } else {
#pragma unroll
                for (int k = 0; k < 6; k++) ev[k] = em[k];
            }
            float o[4] = {as4.x + ad4.x, as4.y + ad4.y, as4.z + ad4.z, as4.w + ad4.w};
#pragma unroll
            for (int h = 0; h < 4; h++) {
#pragma unroll
                for (int k = 0; k < 6; k++) o[h] += ev[k] * Wea[k * 4 + h];
                o[h] = o[h] > 0.f ? o[h] : 0.2f * o[h];
            }
            *(float4*)&al[(size_t)i * 4] = make_float4(o[0], o[1], o[2], o[3]);
            m0 = fmaxf(m0, o[0]); m1 = fmaxf(m1, o[1]);
            m2 = fmaxf(m2, o[2]); m3 = fmaxf(m3, o[3]);
        }
#pragma unroll
        for (int off = 32; off; off >>= 1) {
            m0 = fmaxf(m0, __shfl_xor(m0, off)); m1 = fmaxf(m1, __shfl_xor(m1, off));
            m2 = fmaxf(m2, __shfl_xor(m2, off)); m3 = fmaxf(m3, __shfl_xor(m3, off));
        }
        float s0 = 0.f, s1 = 0.f, s2 = 0.f, s3 = 0.f;
        for (int i = b + lane; i < e; i += 64) {
            float4 v = *(const float4*)&al[(size_t)i * 4];
            s0 += __expf(v.x - m0); s1 += __expf(v.y - m1);
            s2 += __expf(v.z - m2); s3 += __expf(v.w - m3);
        }
#pragma unroll
        for (int off = 32; off; off >>= 1) {
            s0 += __shfl_xor(s0, off); s1 += __shfl_xor(s1, off);
            s2 += __shfl_xor(s2, off); s3 += __shfl_xor(s3, off);
        }
        float r0 = 1.f / (s0 + 1e-16f), r1 = 1.f / (s1 + 1e-16f);
        float r2 = 1.f / (s2 + 1e-16f), r3 = 1.f / (s3 + 1e-16f);
        float mh = (hpre == 0) ? m0 : (hpre == 1) ? m1 : (hpre == 2) ? m2 : m3;
        float rh = (hpre == 0) ? r0 : (hpre == 1) ? r1 : (hpre == 2) ? r2 : r3;

        for (int base = b; base < e; base += 64) {
            int c = e - base; if (c > 64) c = 64;
            int spre = (base + lane < e) ? ssrc[base + lane] : wid;
            float wpre[4];
#pragma unroll
            for (int q = 0; q < 4; q++) {
                int idx = base + q * 16 + m15;
                wpre[q] = (idx < e) ? __expf(al[(size_t)idx * 4 + hpre] - mh) * rh : 0.f;
            }
            accum_window(spre, wpre, (c + 7) & ~7);
        }
    }

    // ---------- epilogue: bias + BN + ELU + bf16 store ----------
    float acc[CPL];
#pragma unroll
    for (int k = 0; k < CPL / 2; k++) { acc[2 * k] = acc2[k][0]; acc[2 * k + 1] = acc2[k][1]; }
    int base_c = lane * CPL;
    unsigned int opk[CPL / 2];
#pragma unroll
    for (int q = 0; q < CPL / 4; q++) {
        float4 bi = *(const float4*)&bias[base_c + q * 4];
        float4 ga = *(const float4*)&gam[base_c + q * 4];
        float4 be = *(const float4*)&bet[base_c + q * 4];
        float vv[4];
        vv[0] = ga.x * (acc[q * 4 + 0] + bi.x) * RSQ + be.x;
        vv[1] = ga.y * (acc[q * 4 + 1] + bi.y) * RSQ + be.y;
        vv[2] = ga.z * (acc[q * 4 + 2] + bi.z) * RSQ + be.z;
        vv[3] = ga.w * (acc[q * 4 + 3] + bi.w) * RSQ + be.w;
#pragma unroll
        for (int k = 0; k < 4; k++) vv[k] = vv[k] > 0.f ? vv[k] : (__expf(vv[k]) - 1.0f);
        opk[q * 2 + 0] = (unsigned int)f2bf(vv[0]) | ((unsigned int)f2bf(vv[1]) << 16);
        opk[q * 2 + 1] = (unsigned int)f2bf(vv[2]) | ((unsigned int)f2bf(vv[3]) << 16);
    }
    if constexpr (CPL == 4) {
        *(uint2*)&hout[(size_t)wid * HC + base_c] = make_uint2(opk[0], opk[1]);
    } else {
        *(uint4*)&hout[(size_t)wid * HC + base_c] = make_uint4(opk[0], opk[1], opk[2], opk[3]);
    }
}

// ----------------------------------------------------------- pooling + head

__global__ void bounds_kernel(const int* __restrict__ batch, int* __restrict__ first,
                              int* __restrict__ last) {
    int n = blockIdx.x * blockDim.x + threadIdx.x;
    if (n >= NN) return;
    int b = batch[n];
    if (n == 0 || batch[n - 1] != b) first[b] = n;
    if (n == NN - 1 || batch[n + 1] != b) last[b] = n;
}

#define PCHUNK 64
__global__ __launch_bounds__(256) void pool_kernel(const unsigned short* __restrict__ h3,
                                                   const int* __restrict__ batch,
                                                   float* __restrict__ pooled) {
    int c = threadIdx.x;
    int n0 = blockIdx.x * PCHUNK;
    int nend = min(n0 + PCHUNK, NN);
    if (n0 >= NN) return;
    float local = 0.f;
    int curg = batch[n0];
    for (int n = n0; n < nend; n++) {
        int g = batch[n];
        if (g != curg) {
            atomicAdd(&pooled[(size_t)curg * 256 + c], local);
            local = 0.f;
            curg = g;
        }
        local += bf2f(h3[(size_t)n * 256 + c]);
    }
    atomicAdd(&pooled[(size_t)curg * 256 + c], local);
}

__global__ void final_kernel(const float* __restrict__ pooled,
                             const int* __restrict__ first, const int* __restrict__ last,
                             const float* __restrict__ Wf1, const float* __restrict__ bf1,
                             const float* __restrict__ gf, const float* __restrict__ bbf,
                             const float* __restrict__ Wf2, const float* __restrict__ bf2,
                             float* __restrict__ out) {
    int g = blockIdx.x;
    int j = threadIdx.x;  // 32 threads
    __shared__ float hh[32];
    float c = fmaxf((float)(last[g] - first[g] + 1), 1.0f);
    float inv = 1.0f / c;
    float acc = bf1[j];
    for (int i = 0; i < 256; i++) acc += (pooled[(size_t)g * 256 + i] * inv) * Wf1[(size_t)i * 32 + j];
    float v = gf[j] * acc * RSQ + bbf[j];
    hh[j] = v > 0.f ? v : (__expf(v) - 1.0f);
    __syncthreads();
    if (j == 0) {
        float l0 = bf2[0], l1 = bf2[1];
        for (int i = 0; i < 32; i++) {
            l0 += hh[i] * Wf2[i * 2 + 0];
            l1 += hh[i] * Wf2[i * 2 + 1];
        }
        float mx = fmaxf(l0, l1);
        float lse = mx + logf(__expf(l0 - mx) + __expf(l1 - mx));
        out[g * 2 + 0] = l0 - lse;
        out[g * 2 + 1] = l1 - lse;
    }
}

// -------------------------------------------------------------------- launch

extern "C" void kernel_launch(void* const* d_in, const int* in_sizes, int n_in,
                              void* d_out, int out_size, void* d_ws, size_t ws_size,
                              hipStream_t stream) {
    (void)in_sizes; (void)n_in; (void)out_size; (void)ws_size;

    const float* x  = (const float*)d_in[0];
    const float* ef = (const float*)d_in[1];
    const float* W_[3]  = {(const float*)d_in[2],  (const float*)d_in[10], (const float*)d_in[18]};
    const float* We_[3] = {(const float*)d_in[3],  (const float*)d_in[11], (const float*)d_in[19]};
    const float* As_[3] = {(const float*)d_in[4],  (const float*)d_in[12], (const float*)d_in[20]};
    const float* Ad_[3] = {(const float*)d_in[5],  (const float*)d_in[13], (const float*)d_in[21]};
    const float* Ae_[3] = {(const float*)d_in[6],  (const float*)d_in[14], (const float*)d_in[22]};
    const float* Bi_[3] = {(const float*)d_in[7],  (const float*)d_in[15], (const float*)d_in[23]};
    const float* Ga_[3] = {(const float*)d_in[8],  (const float*)d_in[16], (const float*)d_in[24]};
    const float* Be_[3] = {(const float*)d_in[9],  (const float*)d_in[17], (const float*)d_in[25]};
    const float* Wf1 = (const float*)d_in[26];
    const float* bf1 = (const float*)d_in[27];
    const float* gf  = (const float*)d_in[28];
    const float* bbf = (const float*)d_in[29];
    const float* Wf2 = (const float*)d_in[30];
    const float* bf2 = (const float*)d_in[31];
    const int* eidx  = (const int*)d_in[32];
    const int* src0  = eidx;
    const int* dst0  = eidx + EE;
    const int* batch = (const int*)d_in[33];
    float* out = (float*)d_out;

    char* p = (char*)d_ws;
    unsigned short* B0 = (unsigned short*)carve(p, (size_t)NPAD * 512 * 2);
    unsigned short* B2 = (unsigned short*)carve(p, (size_t)NPAD * 512 * 2);
    unsigned char*  X8 = (unsigned char*)carve(p, (size_t)NPAD * 512);
    unsigned short* Wt1 = (unsigned short*)carve(p, (size_t)256 * 64 * 2);
    unsigned short* Wt2 = (unsigned short*)carve(p, (size_t)512 * 256 * 2);
    unsigned short* Wt3 = (unsigned short*)carve(p, (size_t)256 * 512 * 2);
    float* al     = (float*)carve(p, (size_t)ET * 4 * 4);
    float* efc    = (float*)carve(p, (size_t)ET * 6 * 4);
    float* als    = (float*)carve(p, (size_t)NN * 4 * 4);
    float* ald    = (float*)carve(p, (size_t)NN * 4 * 4);
    float* wea    = (float*)carve(p, 3 * 24 * 4);
    float* pooled = (float*)carve(p, (size_t)GG * 256 * 4);
    int* first  = (int*)carve(p, (size_t)GG * 4);
    int* last   = (int*)carve(p, (size_t)GG * 4);
    int* deg    = (int*)carve(p, (size_t)NN * 4);
    int* rowptr = (int*)carve(p, (size_t)(NN + 1) * 4);
    int* epos   = (int*)carve(p, (size_t)EE * 4);
    int* ssrc   = (int*)carve(p, (size_t)ET * 4);
    int* bsum   = (int*)carve(p, 512);

    zero_kernel<<<(NN + GG * 256 + 2 * GG + 255) / 256, 256, 0, stream>>>(deg, pooled, first, last);

    deg_kernel<<<(EE + 255) / 256, 256, 0, stream>>>(dst0, deg, epos);

    int nb = (NN + SCAN_B - 1) / SCAN_B;  // 98
    scan1_kernel<<<nb, SCAN_B, 0, stream>>>(deg, rowptr, bsum, NN);
    scan2_kernel<<<1, 128, 0, stream>>>(bsum, nb);
    scan3_kernel<<<nb, SCAN_B, 0, stream>>>(rowptr, bsum, NN);
    fill_kernel<<<(ET + 255) / 256, 256, 0, stream>>>(src0, dst0, rowptr, epos, deg, ef,
                                                      ssrc, efc);

    prep_kernel<<<(PREP_T + 255) / 256, 256, 0, stream>>>(x, W_[0], W_[1], W_[2],
                                                          We_[0], Ae_[0], We_[1], Ae_[1],
                                                          We_[2], Ae_[2],
                                                          B0, Wt1, Wt2, Wt3, wea);

    const int fpad[3] = {64, 256, 512};
    const int HCs[3] = {256, 512, 256};
    const int Cs[3]  = {64, 128, 64};
    const unsigned short* Wts[3] = {Wt1, Wt2, Wt3};
    const unsigned short* inb[3]  = {B0, B2, B0};
    unsigned short* outb[3]       = {B2, B0, B2};

    for (int li = 0; li < 3; li++) {
        int Kp = fpad[li], HC = HCs[li];
        dim3 gg(NPAD / 128, HC / 128);
        if (Cs[li] == 64)
            gemm_fused_kernel<64><<<gg, 256, 0, stream>>>(inb[li], Wts[li], X8,
                                                          As_[li], Ad_[li], als, ald, Kp);
        else
            gemm_fused_kernel<128><<<gg, 256, 0, stream>>>(inb[li], Wts[li], X8,
                                                           As_[li], Ad_[li], als, ald, Kp);

        if (Cs[li] == 64)
            aggregate_fused_kernel<64><<<NN, 64, 0, stream>>>(
                X8, rowptr, ssrc, efc, wea + li * 24, als, ald, al,
                Bi_[li], Ga_[li], Be_[li], outb[li]);
        else
            aggregate_fused_kernel<128><<<NN, 64, 0, stream>>>(
                X8, rowptr, ssrc, efc, wea + li * 24, als, ald, al,
                Bi_[li], Ga_[li], Be_[li], outb[li]);
    }

    bounds_kernel<<<(NN + 255) / 256, 256, 0, stream>>>(batch, first, last);
    pool_kernel<<<(NN + PCHUNK - 1) / PCHUNK, 256, 0, stream>>>(B2, batch, pooled);
    final_kernel<<<GG, 32, 0, stream>>>(pooled, first, last, Wf1, bf1, gf, bbf, Wf2, bf2, out);
}